// Round 2
// baseline (2084.201 us; speedup 1.0000x reference)
//
#include <hip/hip_runtime.h>
#include <hip/hip_bf16.h>
#include <math.h>

// Problem dims (fixed by reference)
constexpr int Bc = 2, Tc = 1024, Dc = 1024, Hc = 8, DKc = 128, DVc = 256;
constexpr int BT = Bc * Tc;                 // 2048 rows
constexpr float QSCALE = 0.08838834764831845f;  // 128^-0.5

// ---------------- workspace layout (float offsets) ----------------
// High-water: 16M floats + eg/beta ~= 64.1 MB.
//   qpre [2048,1024] kpre [2048,1024] vpre [2048,2048] q k v eg beta
// aliases: o -> qpre+kpre (dead after conv) ; gv -> vpre (dead after conv_v) ;
//          oo -> v (dead after recurrence)
constexpr size_t OF_QPRE = 0;                       // 2M floats
constexpr size_t OF_KPRE = 2097152;                 // 2M
constexpr size_t OF_VPRE = 4194304;                 // 4M
constexpr size_t OF_Q    = 8388608;                 // 2M
constexpr size_t OF_K    = 10485760;                // 2M
constexpr size_t OF_V    = 12582912;                // 4M
constexpr size_t OF_EG   = 16777216;                // 16K
constexpr size_t OF_BETA = 16793600;                // 16K
constexpr size_t OF_O    = OF_QPRE;                 // alias (4M)
constexpr size_t OF_GV   = OF_VPRE;                 // alias (4M)
constexpr size_t OF_OO   = OF_V;                    // alias (4M)

// ---------------- fp32 tiled GEMM: C[M,N] = A[M,K] @ B[K,N] ----------------
// 128x128 tile, K-tile 8, 256 threads, 8x8 micro-tile.
__global__ __launch_bounds__(256) void gemm_f32(const float* __restrict__ A,
                                                const float* __restrict__ B,
                                                float* __restrict__ C,
                                                int M, int N, int Kd) {
  __shared__ float As[8][128];
  __shared__ float Bs[8][128];
  const int tid = threadIdx.x;
  const int m0 = blockIdx.y * 128;
  const int n0 = blockIdx.x * 128;
  const int tm = (tid >> 4) * 8;   // 0..120
  const int tn = (tid & 15) * 8;   // 0..120
  float acc[8][8] = {};
  for (int k0 = 0; k0 < Kd; k0 += 8) {
    {  // A tile: 128 rows x 8 k, float4 along K
      int r  = tid >> 1;
      int kq = (tid & 1) * 4;
      float4 a4 = *(const float4*)&A[(size_t)(m0 + r) * Kd + k0 + kq];
      As[kq + 0][r] = a4.x; As[kq + 1][r] = a4.y;
      As[kq + 2][r] = a4.z; As[kq + 3][r] = a4.w;
    }
    {  // B tile: 8 k x 128 n
      int kk = tid >> 5;
      int nq = (tid & 31) * 4;
      *(float4*)&Bs[kk][nq] = *(const float4*)&B[(size_t)(k0 + kk) * N + n0 + nq];
    }
    __syncthreads();
#pragma unroll
    for (int kk = 0; kk < 8; ++kk) {
      float a[8], b[8];
      *(float4*)&a[0] = *(const float4*)&As[kk][tm];
      *(float4*)&a[4] = *(const float4*)&As[kk][tm + 4];
      *(float4*)&b[0] = *(const float4*)&Bs[kk][tn];
      *(float4*)&b[4] = *(const float4*)&Bs[kk][tn + 4];
#pragma unroll
      for (int i = 0; i < 8; ++i)
#pragma unroll
        for (int j = 0; j < 8; ++j) acc[i][j] = fmaf(a[i], b[j], acc[i][j]);
    }
    __syncthreads();
  }
  for (int i = 0; i < 8; ++i) {
    float4* cp = (float4*)&C[(size_t)(m0 + tm + i) * N + n0 + tn];
    cp[0] = *(float4*)&acc[i][0];
    cp[1] = *(float4*)&acc[i][4];
  }
}

// ---------------- depthwise causal conv1d (K=4) + silu ----------------
// X,Y: [B,T,C]; W: [C,4]. Thread per channel, 32-timestep chunk, rolling window.
__global__ __launch_bounds__(256) void conv_silu(const float* __restrict__ X,
                                                 const float* __restrict__ W,
                                                 float* __restrict__ Y, int C) {
  int c = blockIdx.x * 256 + threadIdx.x;
  if (c >= C) return;
  int b  = blockIdx.z;
  int t0 = blockIdx.y * 32;
  float4 w = *(const float4*)&W[c * 4];
  const float* xp = X + (size_t)b * Tc * C + c;
  float* yp = Y + (size_t)b * Tc * C + c;
  float x0 = (t0 >= 3) ? xp[(size_t)(t0 - 3) * C] : 0.f;
  float x1 = (t0 >= 2) ? xp[(size_t)(t0 - 2) * C] : 0.f;
  float x2 = (t0 >= 1) ? xp[(size_t)(t0 - 1) * C] : 0.f;
  for (int t = t0; t < t0 + 32; ++t) {
    float x3 = xp[(size_t)t * C];
    float a  = w.x * x0 + w.y * x1 + w.z * x2 + w.w * x3;
    float y  = a / (1.f + __expf(-a));   // silu
    yp[(size_t)t * C] = y;
    x0 = x1; x1 = x2; x2 = x3;
  }
}

// ---------------- beta + exp(g) (tiny GEMMs fused): one wave per (b,t,h) ----------------
__global__ __launch_bounds__(256) void beta_g_kernel(const float* __restrict__ X,
                                                     const float* __restrict__ Wb,
                                                     const float* __restrict__ Wa,
                                                     const float* __restrict__ A_log,
                                                     const float* __restrict__ dt_bias,
                                                     float* __restrict__ beta,
                                                     float* __restrict__ eg) {
  int w    = blockIdx.x * 4 + (threadIdx.x >> 6);  // bt*H + h
  int lane = threadIdx.x & 63;
  int h  = w & 7;
  int bt = w >> 3;
  const float* x = X + (size_t)bt * Dc;
  float sb = 0.f, sa = 0.f;
#pragma unroll
  for (int i = 0; i < 16; ++i) {
    int d = lane + 64 * i;
    float xv = x[d];
    sb = fmaf(xv, Wb[d * 8 + h], sb);
    sa = fmaf(xv, Wa[d * 8 + h], sa);
  }
#pragma unroll
  for (int m = 1; m < 64; m <<= 1) {
    sb += __shfl_xor(sb, m);
    sa += __shfl_xor(sa, m);
  }
  if (lane == 0) {
    beta[w] = 1.f / (1.f + expf(-sb));
    float z  = sa + dt_bias[h];
    float sp = (z > 20.f) ? z : log1pf(expf(z));
    eg[w]    = expf(-expf(A_log[h]) * sp);
  }
}

// ---------------- l2norm over DK for q (with scale) and k: one wave per (b,t,h) ----------------
__global__ __launch_bounds__(256) void l2norm_qk(float* __restrict__ Q, float* __restrict__ K) {
  int w    = blockIdx.x * 4 + (threadIdx.x >> 6);  // bt*H + h
  int lane = threadIdx.x & 63;
  int h = w & 7;
  size_t bt = (size_t)(w >> 3);
  float* qp = Q + bt * (Hc * DKc) + h * DKc + lane * 2;
  float* kp = K + bt * (Hc * DKc) + h * DKc + lane * 2;
  float2 q2 = *(float2*)qp;
  float2 k2 = *(float2*)kp;
  float sq = q2.x * q2.x + q2.y * q2.y;
  float sk = k2.x * k2.x + k2.y * k2.y;
#pragma unroll
  for (int m = 1; m < 64; m <<= 1) {
    sq += __shfl_xor(sq, m);
    sk += __shfl_xor(sk, m);
  }
  float rq = rsqrtf(sq + 1e-6f) * QSCALE;
  float rk = rsqrtf(sk + 1e-6f);
  q2.x *= rq; q2.y *= rq;
  k2.x *= rk; k2.y *= rk;
  *(float2*)qp = q2;
  *(float2*)kp = k2;
}

// ---------------- gated delta rule recurrence ----------------
// One wave per state COLUMN (b,h,j): S[:,j] (128 floats, 2/lane).
// Per step: S' = eg*S ; u = beta*(v_j - k.S') ; S = S' + k*u ; o_j = q.S' + (q.k)*u
// Single interleaved butterfly for the 3 reductions.
__global__ __launch_bounds__(256) void delta_recurrence(const float* __restrict__ Q,
                                                        const float* __restrict__ K,
                                                        const float* __restrict__ V,
                                                        const float* __restrict__ EG,
                                                        const float* __restrict__ BETA,
                                                        float* __restrict__ O) {
  int widx = threadIdx.x >> 6, lane = threadIdx.x & 63;
  int gw = blockIdx.x * 4 + widx;   // global column id in [0, 4096)
  int bh = gw >> 8;                 // b*H + h
  int j  = gw & 255;
  int b = bh >> 3, h = bh & 7;
  const float* qp  = Q    + (size_t)b * Tc * 1024 + h * 128 + lane * 2;
  const float* kp  = K    + (size_t)b * Tc * 1024 + h * 128 + lane * 2;
  const float* vp  = V    + (size_t)b * Tc * 2048 + h * 256 + j;
  const float* egp = EG   + (size_t)b * Tc * 8 + h;
  const float* bp  = BETA + (size_t)b * Tc * 8 + h;
  float* op        = O    + (size_t)b * Tc * 2048 + h * 256 + j;

  float s0 = 0.f, s1 = 0.f;
  // prefetch t=0
  float2 q2 = *(const float2*)qp;
  float2 k2 = *(const float2*)kp;
  float vt = *vp, egt = *egp, btv = *bp;

  for (int t = 0; t < Tc; ++t) {
    int tn = (t + 1 < Tc) ? t + 1 : t;  // safe prefetch
    float2 q2n = *(const float2*)(qp + (size_t)tn * 1024);
    float2 k2n = *(const float2*)(kp + (size_t)tn * 1024);
    float vtn  = vp[(size_t)tn * 2048];
    float egn  = egp[(size_t)tn * 8];
    float btn  = bp[(size_t)tn * 8];

    float ss0 = s0 * egt, ss1 = s1 * egt;
    float pk  = k2.x * ss0 + k2.y * ss1;
    float pq  = q2.x * ss0 + q2.y * ss1;
    float pqk = q2.x * k2.x + q2.y * k2.y;
#pragma unroll
    for (int m = 1; m < 64; m <<= 1) {
      pk  += __shfl_xor(pk, m);
      pq  += __shfl_xor(pq, m);
      pqk += __shfl_xor(pqk, m);
    }
    float u = btv * (vt - pk);
    s0 = ss0 + k2.x * u;
    s1 = ss1 + k2.y * u;
    float oj = pq + pqk * u;
    if (lane == 0) op[(size_t)t * 2048] = oj;

    q2 = q2n; k2 = k2n; vt = vtn; egt = egn; btv = btn;
  }
}

// ---------------- fused gated RMSNorm: one wave per (b,t,h) ----------------
__global__ __launch_bounds__(256) void gated_rmsnorm(const float* __restrict__ O,
                                                     const float* __restrict__ GV,
                                                     const float* __restrict__ NW,
                                                     float* __restrict__ OO) {
  int w    = blockIdx.x * 4 + (threadIdx.x >> 6);  // bt*H + h
  int lane = threadIdx.x & 63;
  size_t base = (size_t)w * DVc;
  float4 o4 = *(const float4*)&O[base + lane * 4];
  float ss = o4.x * o4.x + o4.y * o4.y + o4.z * o4.z + o4.w * o4.w;
#pragma unroll
  for (int m = 1; m < 64; m <<= 1) ss += __shfl_xor(ss, m);
  float r = rsqrtf(ss * (1.f / 256.f) + 1e-5f);
  float4 g4 = *(const float4*)&GV[base + lane * 4];
  float4 w4 = *(const float4*)&NW[lane * 4];
  float4 out;
  out.x = o4.x * r * w4.x * (g4.x / (1.f + __expf(-g4.x)));
  out.y = o4.y * r * w4.y * (g4.y / (1.f + __expf(-g4.y)));
  out.z = o4.z * r * w4.z * (g4.z / (1.f + __expf(-g4.z)));
  out.w = o4.w * r * w4.w * (g4.w / (1.f + __expf(-g4.w)));
  *(float4*)&OO[base + lane * 4] = out;
}

// ---------------- launcher ----------------
extern "C" void kernel_launch(void* const* d_in, const int* in_sizes, int n_in,
                              void* d_out, int out_size, void* d_ws, size_t ws_size,
                              hipStream_t stream) {
  const float* x       = (const float*)d_in[0];
  const float* Wq      = (const float*)d_in[1];
  const float* Wk      = (const float*)d_in[2];
  const float* Wv      = (const float*)d_in[3];
  const float* conv_q  = (const float*)d_in[4];
  const float* conv_k  = (const float*)d_in[5];
  const float* conv_v  = (const float*)d_in[6];
  const float* Wb      = (const float*)d_in[7];
  const float* Wa      = (const float*)d_in[8];
  const float* A_log   = (const float*)d_in[9];
  const float* dt_bias = (const float*)d_in[10];
  const float* Wg      = (const float*)d_in[11];
  const float* norm_w  = (const float*)d_in[12];
  const float* Wo      = (const float*)d_in[13];
  float* out = (float*)d_out;
  float* ws  = (float*)d_ws;

  float* qpre = ws + OF_QPRE;
  float* kpre = ws + OF_KPRE;
  float* vpre = ws + OF_VPRE;
  float* q    = ws + OF_Q;
  float* k    = ws + OF_K;
  float* v    = ws + OF_V;
  float* eg   = ws + OF_EG;
  float* beta = ws + OF_BETA;
  float* o    = ws + OF_O;    // aliases qpre+kpre (dead after conv)
  float* gv   = ws + OF_GV;   // aliases vpre (dead after conv_v)
  float* oo   = ws + OF_OO;   // aliases v (dead after recurrence)

  dim3 blk(256);

  // 1-3: projections q,k,v
  gemm_f32<<<dim3(1024 / 128, BT / 128), blk, 0, stream>>>(x, Wq, qpre, BT, 1024, 1024);
  gemm_f32<<<dim3(1024 / 128, BT / 128), blk, 0, stream>>>(x, Wk, kpre, BT, 1024, 1024);
  gemm_f32<<<dim3(2048 / 128, BT / 128), blk, 0, stream>>>(x, Wv, vpre, BT, 2048, 1024);

  // 4: beta + exp(g)
  beta_g_kernel<<<dim3(BT * Hc / 4), blk, 0, stream>>>(x, Wb, Wa, A_log, dt_bias, beta, eg);

  // 5-7: causal conv + silu
  conv_silu<<<dim3(1024 / 256, Tc / 32, Bc), blk, 0, stream>>>(qpre, conv_q, q, 1024);
  conv_silu<<<dim3(1024 / 256, Tc / 32, Bc), blk, 0, stream>>>(kpre, conv_k, k, 1024);
  conv_silu<<<dim3(2048 / 256, Tc / 32, Bc), blk, 0, stream>>>(vpre, conv_v, v, 2048);

  // 8: l2norm q (scaled) and k
  l2norm_qk<<<dim3(BT * Hc / 4), blk, 0, stream>>>(q, k);

  // 9: gv = x @ Wg  (after conv_v: gv aliases vpre)
  gemm_f32<<<dim3(2048 / 128, BT / 128), blk, 0, stream>>>(x, Wg, gv, BT, 2048, 1024);

  // 10: gated delta rule recurrence  (o aliases qpre/kpre, dead after conv)
  delta_recurrence<<<dim3(Bc * Hc * DVc / 4), blk, 0, stream>>>(q, k, v, eg, beta, o);

  // 11: gated rmsnorm  (oo aliases v, dead after recurrence)
  gated_rmsnorm<<<dim3(BT * Hc / 4), blk, 0, stream>>>(o, gv, norm_w, oo);

  // 12: out = oo @ Wo
  gemm_f32<<<dim3(1024 / 128, BT / 128), blk, 0, stream>>>(oo, Wo, out, BT, 1024, 2048);
}

// Round 3
// 1490.049 us; speedup vs baseline: 1.3987x; 1.3987x over previous
//
#include <hip/hip_runtime.h>
#include <hip/hip_bf16.h>
#include <math.h>

// Problem dims (fixed by reference)
constexpr int Bc = 2, Tc = 1024, Dc = 1024, Hc = 8, DKc = 128, DVc = 256;
constexpr int BT_ROWS = Bc * Tc;                // 2048 rows
constexpr float QSCALE = 0.08838834764831845f;  // 128^-0.5
constexpr int NCHUNK = 16, CHUNK = 64;          // T = 16 chunks of 64

// ---------------- workspace layout (float offsets), extent = 67.24MB (proven safe) ----
// 0..2M   : qpre  -> KbarT (phase1 out)       [qpre dead after conv_q]
// 2..3M   : kpre  -> BT    (phase1 out)       [kpre dead after conv_k]
// 3M+     : kpre  -> CS    (phase1 out, 16K)
// 4..8M   : vpre  -> o     (phase2 out)       [vpre dead after conv_v]
// 8..10M  : q     -> oo half                  [q read through phase2]
// 10..12M : k     -> oo half                  [k read through phase2]
// 12..16M : v     -> vbar (phase1 in-place) -> gv (gemm after phase2)
// 16M     : g_log (16K) ; 16M+16K : beta (16K)
constexpr size_t OF_QPRE  = 0;
constexpr size_t OF_KPRE  = 2097152;
constexpr size_t OF_VPRE  = 4194304;
constexpr size_t OF_Q     = 8388608;
constexpr size_t OF_K     = 10485760;
constexpr size_t OF_V     = 12582912;
constexpr size_t OF_G     = 16777216;
constexpr size_t OF_BETA  = 16793600;
constexpr size_t OF_KBART = OF_QPRE;            // 256 chunks * 128 * 64 = 2M
constexpr size_t OF_BT    = OF_KPRE;            // 256 * 64 * 64 = 1M
constexpr size_t OF_CS    = OF_KPRE + 1048576;  // 256 * 64 = 16K
constexpr size_t OF_O     = OF_VPRE;            // 4M
constexpr size_t OF_OO    = OF_Q;               // 4M over q+k (after phase2)
constexpr size_t OF_GV    = OF_V;               // 4M over v (after phase2)

// ---------------- fp32 tiled GEMM: C[M,N] = A[M,K] @ B[K,N] ----------------
__global__ __launch_bounds__(256) void gemm_f32(const float* __restrict__ A,
                                                const float* __restrict__ B,
                                                float* __restrict__ C,
                                                int M, int N, int Kd) {
  __shared__ float As[8][128];
  __shared__ float Bs[8][128];
  const int tid = threadIdx.x;
  const int m0 = blockIdx.y * 128;
  const int n0 = blockIdx.x * 128;
  const int tm = (tid >> 4) * 8;
  const int tn = (tid & 15) * 8;
  float acc[8][8] = {};
  for (int k0 = 0; k0 < Kd; k0 += 8) {
    {
      int r  = tid >> 1;
      int kq = (tid & 1) * 4;
      float4 a4 = *(const float4*)&A[(size_t)(m0 + r) * Kd + k0 + kq];
      As[kq + 0][r] = a4.x; As[kq + 1][r] = a4.y;
      As[kq + 2][r] = a4.z; As[kq + 3][r] = a4.w;
    }
    {
      int kk = tid >> 5;
      int nq = (tid & 31) * 4;
      *(float4*)&Bs[kk][nq] = *(const float4*)&B[(size_t)(k0 + kk) * N + n0 + nq];
    }
    __syncthreads();
#pragma unroll
    for (int kk = 0; kk < 8; ++kk) {
      float a[8], b[8];
      *(float4*)&a[0] = *(const float4*)&As[kk][tm];
      *(float4*)&a[4] = *(const float4*)&As[kk][tm + 4];
      *(float4*)&b[0] = *(const float4*)&Bs[kk][tn];
      *(float4*)&b[4] = *(const float4*)&Bs[kk][tn + 4];
#pragma unroll
      for (int i = 0; i < 8; ++i)
#pragma unroll
        for (int j = 0; j < 8; ++j) acc[i][j] = fmaf(a[i], b[j], acc[i][j]);
    }
    __syncthreads();
  }
  for (int i = 0; i < 8; ++i) {
    float4* cp = (float4*)&C[(size_t)(m0 + tm + i) * N + n0 + tn];
    cp[0] = *(float4*)&acc[i][0];
    cp[1] = *(float4*)&acc[i][4];
  }
}

// ---------------- depthwise causal conv1d (K=4) + silu ----------------
__global__ __launch_bounds__(256) void conv_silu(const float* __restrict__ X,
                                                 const float* __restrict__ W,
                                                 float* __restrict__ Y, int C) {
  int c = blockIdx.x * 256 + threadIdx.x;
  if (c >= C) return;
  int b  = blockIdx.z;
  int t0 = blockIdx.y * 32;
  float4 w = *(const float4*)&W[c * 4];
  const float* xp = X + (size_t)b * Tc * C + c;
  float* yp = Y + (size_t)b * Tc * C + c;
  float x0 = (t0 >= 3) ? xp[(size_t)(t0 - 3) * C] : 0.f;
  float x1 = (t0 >= 2) ? xp[(size_t)(t0 - 2) * C] : 0.f;
  float x2 = (t0 >= 1) ? xp[(size_t)(t0 - 1) * C] : 0.f;
  for (int t = t0; t < t0 + 32; ++t) {
    float x3 = xp[(size_t)t * C];
    float a  = w.x * x0 + w.y * x1 + w.z * x2 + w.w * x3;
    float y  = a / (1.f + __expf(-a));
    yp[(size_t)t * C] = y;
    x0 = x1; x1 = x2; x2 = x3;
  }
}

// ---------------- beta + g_log: one wave per (b,t,h) ----------------
__global__ __launch_bounds__(256) void beta_g_kernel(const float* __restrict__ X,
                                                     const float* __restrict__ Wb,
                                                     const float* __restrict__ Wa,
                                                     const float* __restrict__ A_log,
                                                     const float* __restrict__ dt_bias,
                                                     float* __restrict__ beta,
                                                     float* __restrict__ glog) {
  int w    = blockIdx.x * 4 + (threadIdx.x >> 6);
  int lane = threadIdx.x & 63;
  int h  = w & 7;
  int bt = w >> 3;
  const float* x = X + (size_t)bt * Dc;
  float sb = 0.f, sa = 0.f;
#pragma unroll
  for (int i = 0; i < 16; ++i) {
    int d = lane + 64 * i;
    float xv = x[d];
    sb = fmaf(xv, Wb[d * 8 + h], sb);
    sa = fmaf(xv, Wa[d * 8 + h], sa);
  }
#pragma unroll
  for (int m = 1; m < 64; m <<= 1) {
    sb += __shfl_xor(sb, m);
    sa += __shfl_xor(sa, m);
  }
  if (lane == 0) {
    beta[w] = 1.f / (1.f + expf(-sb));
    float z  = sa + dt_bias[h];
    float sp = (z > 20.f) ? z : log1pf(expf(z));
    glog[w]  = -expf(A_log[h]) * sp;
  }
}

// ---------------- l2norm q (scaled) and k: one wave per (b,t,h) ----------------
__global__ __launch_bounds__(256) void l2norm_qk(float* __restrict__ Q, float* __restrict__ K) {
  int w    = blockIdx.x * 4 + (threadIdx.x >> 6);
  int lane = threadIdx.x & 63;
  int h = w & 7;
  size_t bt = (size_t)(w >> 3);
  float* qp = Q + bt * (Hc * DKc) + h * DKc + lane * 2;
  float* kp = K + bt * (Hc * DKc) + h * DKc + lane * 2;
  float2 q2 = *(float2*)qp;
  float2 k2 = *(float2*)kp;
  float sq = q2.x * q2.x + q2.y * q2.y;
  float sk = k2.x * k2.x + k2.y * k2.y;
#pragma unroll
  for (int m = 1; m < 64; m <<= 1) {
    sq += __shfl_xor(sq, m);
    sk += __shfl_xor(sk, m);
  }
  float rq = rsqrtf(sq + 1e-6f) * QSCALE;
  float rk = rsqrtf(sk + 1e-6f);
  q2.x *= rq; q2.y *= rq;
  k2.x *= rk; k2.y *= rk;
  *(float2*)qp = q2;
  *(float2*)kp = k2;
}

// ---------------- Phase 1: per (bh, chunk) precompute ----------------
// gamma_i = exp(cumsum g); A[i][s] = beta_i*(g_i/g_s)*(k_i.k_s) (s<i); M=(I+A)^-1
// KbarT[d][i] = sum_s M[i][s]*beta_s*gamma_s*k_s[d]
// BT[s][i]    = (gamma_i/gamma_s)*(q_i.k_s), s<=i (else 0)
// vbar (in-place over V): vbar[i][:] = sum_s M[i][s]*beta_s*v_s[:]
// CS[i] = cumsum g (for phase2 to derive gamma/ratios)
__global__ __launch_bounds__(256) void phase1(const float* __restrict__ Q,
                                              const float* __restrict__ K,
                                              float* __restrict__ V,
                                              const float* __restrict__ G,
                                              const float* __restrict__ BETA,
                                              float* __restrict__ KbarT,
                                              float* __restrict__ BTm,
                                              float* __restrict__ CS) {
  constexpr int SK = 68;  // transposed tile row stride (bank-friendly, 16B-aligned)
  __shared__ float sm[25984];
  float* kcT  = sm;            // [128][68]
  float* qcT  = sm + 8704;     // [128][68]
  float* vld  = sm;            // [64][256] (reuse of kcT/qcT after barrier)
  float* Amat = sm + 17408;    // [64][65]
  float* Mmat = sm + 21568;    // [64][65]
  float* cs   = sm + 25728;    // [64]
  float* gam  = sm + 25792;    // [64]
  float* bet  = sm + 25856;    // [64]
  float* wk   = sm + 25920;    // [64]
  const int tid = threadIdx.x;
  const int c = blockIdx.x, bh = blockIdx.y;
  const int b = bh >> 3, h = bh & 7;
  const int t0 = c * CHUNK;
  const size_t cb = (size_t)bh * NCHUNK + c;

  // (a) load g,beta; stage kcT,qcT transposed
  if (tid < 64) {
    cs[tid]  = G[((size_t)(b * Tc + t0 + tid)) * 8 + h];
    bet[tid] = BETA[((size_t)(b * Tc + t0 + tid)) * 8 + h];
  }
  {
    int r = tid >> 2, dq = (tid & 3) * 32;
    const float4* kg = (const float4*)&K[((size_t)(b * Tc + t0 + r)) * 1024 + h * 128 + dq];
    const float4* qg = (const float4*)&Q[((size_t)(b * Tc + t0 + r)) * 1024 + h * 128 + dq];
#pragma unroll
    for (int m = 0; m < 8; ++m) {
      float4 kv = kg[m], qv = qg[m];
      int d = dq + m * 4;
      kcT[(d + 0) * SK + r] = kv.x; kcT[(d + 1) * SK + r] = kv.y;
      kcT[(d + 2) * SK + r] = kv.z; kcT[(d + 3) * SK + r] = kv.w;
      qcT[(d + 0) * SK + r] = qv.x; qcT[(d + 1) * SK + r] = qv.y;
      qcT[(d + 2) * SK + r] = qv.z; qcT[(d + 3) * SK + r] = qv.w;
    }
  }
  __syncthreads();
  // (b) inclusive cumsum of g
  if (tid == 0) {
    float a = 0.f;
    for (int i = 0; i < 64; ++i) { a += cs[i]; cs[i] = a; }
  }
  __syncthreads();
  // (c) gamma, wk, CS out; A; BT
  if (tid < 64) {
    float gv_ = __expf(cs[tid]);
    gam[tid] = gv_;
    wk[tid]  = bet[tid] * gv_;
    CS[cb * 64 + tid] = cs[tid];
  }
  for (int e = tid; e < 4096; e += 256) {   // A: lanes vary s
    int i = e >> 6, s = e & 63;
    float av = 0.f;
    if (s < i) {
      float acc = 0.f;
      for (int d = 0; d < 128; ++d) acc += kcT[d * SK + i] * kcT[d * SK + s];
      av = bet[i] * __expf(cs[i] - cs[s]) * acc;
    }
    Amat[i * 65 + s] = av;
  }
  for (int e = tid; e < 4096; e += 256) {   // BT: lanes vary i (coalesced write)
    int s = e >> 6, i = e & 63;
    float outv = 0.f;
    if (s <= i) {
      float acc = 0.f;
      for (int d = 0; d < 128; ++d) acc += qcT[d * SK + i] * kcT[d * SK + s];
      outv = __expf(cs[i] - cs[s]) * acc;
    }
    BTm[cb * 4096 + (size_t)s * 64 + i] = outv;
  }
  __syncthreads();
  // (d) M = (I+A)^-1 forward substitution; lane j owns column j (no cross-lane deps)
  if (tid < 64) {
    int j = tid;
    for (int i = 0; i < 64; ++i) {
      float m = (i == j) ? 1.f : 0.f;
      for (int s = 0; s < i; ++s) m -= Amat[i * 65 + s] * Mmat[s * 65 + j];
      Mmat[i * 65 + j] = m;
    }
  }
  __syncthreads();
  // (e) KbarT
  for (int e = tid; e < 2048; e += 256) {   // d = e>>4, i0 = (e&15)*4
    int d = e >> 4, i0 = (e & 15) * 4;
    float a0 = 0, a1 = 0, a2 = 0, a3 = 0;
    for (int s = 0; s < 64; ++s) {
      float kv = wk[s] * kcT[d * SK + s];
      a0 = fmaf(Mmat[(i0 + 0) * 65 + s], kv, a0);
      a1 = fmaf(Mmat[(i0 + 1) * 65 + s], kv, a1);
      a2 = fmaf(Mmat[(i0 + 2) * 65 + s], kv, a2);
      a3 = fmaf(Mmat[(i0 + 3) * 65 + s], kv, a3);
    }
    float4 w4 = {a0, a1, a2, a3};
    *(float4*)&KbarT[cb * 8192 + (size_t)d * 64 + i0] = w4;
  }
  __syncthreads();
  // (f) stage v chunk into LDS (overwrites kcT/qcT region)
  {
    int r = tid >> 2, j0 = (tid & 3) * 64;
    const float4* vg = (const float4*)&V[((size_t)(b * Tc + t0 + r)) * 2048 + h * 256 + j0];
#pragma unroll
    for (int m = 0; m < 16; ++m) *(float4*)&vld[r * 256 + j0 + m * 4] = vg[m];
  }
  __syncthreads();
  // (g) vbar = M diag(beta) v, in-place to V
  for (int e = tid; e < 4096; e += 256) {   // i = e>>6, j0 = (e&63)*4
    int i = e >> 6, j0 = (e & 63) * 4;
    float a0 = 0, a1 = 0, a2 = 0, a3 = 0;
    for (int s = 0; s < 64; ++s) {
      float m_ = Mmat[i * 65 + s] * bet[s];
      float4 vv = *(const float4*)&vld[s * 256 + j0];
      a0 = fmaf(m_, vv.x, a0); a1 = fmaf(m_, vv.y, a1);
      a2 = fmaf(m_, vv.z, a2); a3 = fmaf(m_, vv.w, a3);
    }
    float4 o4 = {a0, a1, a2, a3};
    *(float4*)&V[((size_t)(b * Tc + t0 + i)) * 2048 + h * 256 + j0] = o4;
  }
}

// ---------------- Phase 2: serial-over-chunks, column-parallel ----------------
// Block = (bh, jb): owns 32 value-columns; S[128][32] persists in LDS over 16 chunks.
// Per chunk: u = vbar - Kbar@S ; o = gamma.*(Q@S) + B@u ; S = gammaC*S + K2^T@u
__global__ __launch_bounds__(256) void phase2(const float* __restrict__ KbarT,
                                              const float* __restrict__ BTm,
                                              const float* __restrict__ CS,
                                              const float* __restrict__ Qp,
                                              const float* __restrict__ Kp,
                                              const float* __restrict__ VBAR,
                                              float* __restrict__ O) {
  __shared__ float S[128 * 32];
  __shared__ float KbT[128 * 68];
  __shared__ float QgL[128 * 68];
  __shared__ float K2c[64 * 128];
  __shared__ float BcT[64 * 68];
  __shared__ float u[64 * 32];
  __shared__ float csL[64], rs[64], gamL[64];
  const int tid = threadIdx.x;
  const int jb = blockIdx.x, bh = blockIdx.y;
  const int b = bh >> 3, h = bh & 7;
  const int ti = tid & 15, tj = tid >> 4;          // 16x16 for u/R2/o
  const int i0 = ti * 4, jj0 = tj * 2;
  const int td = tid & 31, d0 = td * 4;            // 32x8 for S-update
  const int jj5 = (tid >> 5) * 4;
  for (int e = tid; e < 4096; e += 256) S[e] = 0.f;

  for (int c = 0; c < NCHUNK; ++c) {
    const size_t cb = (size_t)bh * NCHUNK + c;
    const int t0 = c * CHUNK;
    __syncthreads();   // prev chunk fully done before restaging
    // ---- stage ----
    if (tid < 64) csL[tid] = CS[cb * 64 + tid];
    {
      const float4* g4 = (const float4*)(KbarT + cb * 8192);
      for (int e = tid; e < 2048; e += 256) {
        int d = e >> 4, i4 = (e & 15) * 4;
        *(float4*)&KbT[d * 68 + i4] = g4[e];
      }
      // Q chunk transposed
      int r = tid >> 2, dq = (tid & 3) * 32;
      const float4* qg4 = (const float4*)&Qp[((size_t)(b * Tc + t0 + r)) * 1024 + h * 128 + dq];
#pragma unroll
      for (int m = 0; m < 8; ++m) {
        float4 f = qg4[m];
        int d = dq + m * 4;
        QgL[(d + 0) * 68 + r] = f.x; QgL[(d + 1) * 68 + r] = f.y;
        QgL[(d + 2) * 68 + r] = f.z; QgL[(d + 3) * 68 + r] = f.w;
      }
      // K chunk row-major (raw; decay ratio applied at use via rs[])
      for (int e = tid; e < 2048; e += 256) {
        int s = e >> 5, d4 = (e & 31) * 4;
        float4 f = *(const float4*)&Kp[((size_t)(b * Tc + t0 + s)) * 1024 + h * 128 + d4];
        *(float4*)&K2c[s * 128 + d4] = f;
      }
      const float4* b4 = (const float4*)(BTm + cb * 4096);
      for (int e = tid; e < 1024; e += 256) {
        int s = e >> 4, i4 = (e & 15) * 4;
        *(float4*)&BcT[s * 68 + i4] = b4[e];
      }
    }
    __syncthreads();
    if (tid < 64) {   // consumed only after the u-barrier below
      gamL[tid] = __expf(csL[tid]);
      rs[tid]   = __expf(csL[63] - csL[tid]);
    }
    // ---- u and R2 accumulate ----
    float ua[4][2] = {}, ra[4][2] = {};
    for (int d = 0; d < 128; ++d) {
      float4 kb = *(const float4*)&KbT[d * 68 + i0];
      float4 qg = *(const float4*)&QgL[d * 68 + i0];
      float s0 = S[d * 32 + jj0];
      float s1 = S[d * 32 + jj0 + 1];
      ua[0][0] = fmaf(kb.x, s0, ua[0][0]); ua[0][1] = fmaf(kb.x, s1, ua[0][1]);
      ua[1][0] = fmaf(kb.y, s0, ua[1][0]); ua[1][1] = fmaf(kb.y, s1, ua[1][1]);
      ua[2][0] = fmaf(kb.z, s0, ua[2][0]); ua[2][1] = fmaf(kb.z, s1, ua[2][1]);
      ua[3][0] = fmaf(kb.w, s0, ua[3][0]); ua[3][1] = fmaf(kb.w, s1, ua[3][1]);
      ra[0][0] = fmaf(qg.x, s0, ra[0][0]); ra[0][1] = fmaf(qg.x, s1, ra[0][1]);
      ra[1][0] = fmaf(qg.y, s0, ra[1][0]); ra[1][1] = fmaf(qg.y, s1, ra[1][1]);
      ra[2][0] = fmaf(qg.z, s0, ra[2][0]); ra[2][1] = fmaf(qg.z, s1, ra[2][1]);
      ra[3][0] = fmaf(qg.w, s0, ra[3][0]); ra[3][1] = fmaf(qg.w, s1, ra[3][1]);
    }
#pragma unroll
    for (int r = 0; r < 4; ++r)
#pragma unroll
      for (int cc = 0; cc < 2; ++cc) {
        int i = i0 + r, jj = jj0 + cc;
        float vb = VBAR[((size_t)(b * Tc + t0 + i)) * 2048 + h * 256 + jb * 32 + jj];
        u[i * 32 + jj] = vb - ua[r][cc];
      }
    __syncthreads();
    // ---- o = gamma_i * (Q@S) + B@u ----
    float ba[4][2] = {};
    for (int s = 0; s < 64; ++s) {
      float4 bt = *(const float4*)&BcT[s * 68 + i0];
      float u0 = u[s * 32 + jj0], u1 = u[s * 32 + jj0 + 1];
      ba[0][0] = fmaf(bt.x, u0, ba[0][0]); ba[0][1] = fmaf(bt.x, u1, ba[0][1]);
      ba[1][0] = fmaf(bt.y, u0, ba[1][0]); ba[1][1] = fmaf(bt.y, u1, ba[1][1]);
      ba[2][0] = fmaf(bt.z, u0, ba[2][0]); ba[2][1] = fmaf(bt.z, u1, ba[2][1]);
      ba[3][0] = fmaf(bt.w, u0, ba[3][0]); ba[3][1] = fmaf(bt.w, u1, ba[3][1]);
    }
#pragma unroll
    for (int r = 0; r < 4; ++r)
#pragma unroll
      for (int cc = 0; cc < 2; ++cc) {
        int i = i0 + r, jj = jj0 + cc;
        O[((size_t)(b * Tc + t0 + i)) * 2048 + h * 256 + jb * 32 + jj] =
            gamL[i] * ra[r][cc] + ba[r][cc];
      }
    // ---- S = gammaC*S + K2^T@u  (each element owned by exactly one thread) ----
    float sa[4][4] = {};
    for (int s = 0; s < 64; ++s) {
      float4 k2v = *(const float4*)&K2c[s * 128 + d0];
      float4 uv  = *(const float4*)&u[s * 32 + jj5];
      float rsv = rs[s];
      float u0 = uv.x * rsv, u1 = uv.y * rsv, u2 = uv.z * rsv, u3 = uv.w * rsv;
      sa[0][0] = fmaf(k2v.x, u0, sa[0][0]); sa[0][1] = fmaf(k2v.x, u1, sa[0][1]);
      sa[0][2] = fmaf(k2v.x, u2, sa[0][2]); sa[0][3] = fmaf(k2v.x, u3, sa[0][3]);
      sa[1][0] = fmaf(k2v.y, u0, sa[1][0]); sa[1][1] = fmaf(k2v.y, u1, sa[1][1]);
      sa[1][2] = fmaf(k2v.y, u2, sa[1][2]); sa[1][3] = fmaf(k2v.y, u3, sa[1][3]);
      sa[2][0] = fmaf(k2v.z, u0, sa[2][0]); sa[2][1] = fmaf(k2v.z, u1, sa[2][1]);
      sa[2][2] = fmaf(k2v.z, u2, sa[2][2]); sa[2][3] = fmaf(k2v.z, u3, sa[2][3]);
      sa[3][0] = fmaf(k2v.w, u0, sa[3][0]); sa[3][1] = fmaf(k2v.w, u1, sa[3][1]);
      sa[3][2] = fmaf(k2v.w, u2, sa[3][2]); sa[3][3] = fmaf(k2v.w, u3, sa[3][3]);
    }
    float gC = gamL[63];
#pragma unroll
    for (int r = 0; r < 4; ++r)
#pragma unroll
      for (int cc = 0; cc < 4; ++cc) {
        int idx = (d0 + r) * 32 + jj5 + cc;
        S[idx] = fmaf(gC, S[idx], sa[r][cc]);
      }
  }
}

// ---------------- fused gated RMSNorm ----------------
__global__ __launch_bounds__(256) void gated_rmsnorm(const float* __restrict__ O,
                                                     const float* __restrict__ GV,
                                                     const float* __restrict__ NW,
                                                     float* __restrict__ OO) {
  int w    = blockIdx.x * 4 + (threadIdx.x >> 6);
  int lane = threadIdx.x & 63;
  size_t base = (size_t)w * DVc;
  float4 o4 = *(const float4*)&O[base + lane * 4];
  float ss = o4.x * o4.x + o4.y * o4.y + o4.z * o4.z + o4.w * o4.w;
#pragma unroll
  for (int m = 1; m < 64; m <<= 1) ss += __shfl_xor(ss, m);
  float r = rsqrtf(ss * (1.f / 256.f) + 1e-5f);
  float4 g4 = *(const float4*)&GV[base + lane * 4];
  float4 w4 = *(const float4*)&NW[lane * 4];
  float4 out;
  out.x = o4.x * r * w4.x * (g4.x / (1.f + __expf(-g4.x)));
  out.y = o4.y * r * w4.y * (g4.y / (1.f + __expf(-g4.y)));
  out.z = o4.z * r * w4.z * (g4.z / (1.f + __expf(-g4.z)));
  out.w = o4.w * r * w4.w * (g4.w / (1.f + __expf(-g4.w)));
  *(float4*)&OO[base + lane * 4] = out;
}

// ---------------- launcher ----------------
extern "C" void kernel_launch(void* const* d_in, const int* in_sizes, int n_in,
                              void* d_out, int out_size, void* d_ws, size_t ws_size,
                              hipStream_t stream) {
  const float* x       = (const float*)d_in[0];
  const float* Wq      = (const float*)d_in[1];
  const float* Wk      = (const float*)d_in[2];
  const float* Wv      = (const float*)d_in[3];
  const float* conv_q  = (const float*)d_in[4];
  const float* conv_k  = (const float*)d_in[5];
  const float* conv_v  = (const float*)d_in[6];
  const float* Wb      = (const float*)d_in[7];
  const float* Wa      = (const float*)d_in[8];
  const float* A_log   = (const float*)d_in[9];
  const float* dt_bias = (const float*)d_in[10];
  const float* Wg      = (const float*)d_in[11];
  const float* norm_w  = (const float*)d_in[12];
  const float* Wo      = (const float*)d_in[13];
  float* out = (float*)d_out;
  float* ws  = (float*)d_ws;

  float* qpre  = ws + OF_QPRE;
  float* kpre  = ws + OF_KPRE;
  float* vpre  = ws + OF_VPRE;
  float* q     = ws + OF_Q;
  float* k     = ws + OF_K;
  float* v     = ws + OF_V;
  float* glog  = ws + OF_G;
  float* beta  = ws + OF_BETA;
  float* KbarT = ws + OF_KBART;  // over qpre
  float* BTm   = ws + OF_BT;     // over kpre
  float* CSb   = ws + OF_CS;     // over kpre
  float* o     = ws + OF_O;      // over vpre
  float* oo    = ws + OF_OO;     // over q+k
  float* gv    = ws + OF_GV;     // over v

  dim3 blk(256);

  // projections
  gemm_f32<<<dim3(1024 / 128, BT_ROWS / 128), blk, 0, stream>>>(x, Wq, qpre, BT_ROWS, 1024, 1024);
  gemm_f32<<<dim3(1024 / 128, BT_ROWS / 128), blk, 0, stream>>>(x, Wk, kpre, BT_ROWS, 1024, 1024);
  gemm_f32<<<dim3(2048 / 128, BT_ROWS / 128), blk, 0, stream>>>(x, Wv, vpre, BT_ROWS, 2048, 1024);

  // beta + log-decay
  beta_g_kernel<<<dim3(BT_ROWS * Hc / 4), blk, 0, stream>>>(x, Wb, Wa, A_log, dt_bias, beta, glog);

  // causal conv + silu
  conv_silu<<<dim3(1024 / 256, Tc / 32, Bc), blk, 0, stream>>>(qpre, conv_q, q, 1024);
  conv_silu<<<dim3(1024 / 256, Tc / 32, Bc), blk, 0, stream>>>(kpre, conv_k, k, 1024);
  conv_silu<<<dim3(2048 / 256, Tc / 32, Bc), blk, 0, stream>>>(vpre, conv_v, v, 2048);

  // l2norm q (scaled) and k
  l2norm_qk<<<dim3(BT_ROWS * Hc / 4), blk, 0, stream>>>(q, k);

  // chunked delta rule
  phase1<<<dim3(NCHUNK, Bc * Hc), blk, 0, stream>>>(q, k, v, glog, beta, KbarT, BTm, CSb);
  phase2<<<dim3(8, Bc * Hc), blk, 0, stream>>>(KbarT, BTm, CSb, q, k, v, o);

  // gv = x @ Wg (into v slot, dead after phase2)
  gemm_f32<<<dim3(2048 / 128, BT_ROWS / 128), blk, 0, stream>>>(x, Wg, gv, BT_ROWS, 2048, 1024);

  // gated rmsnorm (oo over q+k, dead after phase2)
  gated_rmsnorm<<<dim3(BT_ROWS * Hc / 4), blk, 0, stream>>>(o, gv, norm_w, oo);

  // out = oo @ Wo
  gemm_f32<<<dim3(1024 / 128, BT_ROWS / 128), blk, 0, stream>>>(oo, Wo, out, BT_ROWS, 1024, 2048);
}

// Round 4
// 838.785 us; speedup vs baseline: 2.4848x; 1.7764x over previous
//
#include <hip/hip_runtime.h>
#include <hip/hip_bf16.h>
#include <math.h>

// Problem dims (fixed by reference)
constexpr int Bc = 2, Tc = 1024, Dc = 1024, Hc = 8, DKc = 128, DVc = 256;
constexpr int BT_ROWS = Bc * Tc;                // 2048 rows
constexpr float QSCALE = 0.08838834764831845f;  // 128^-0.5
constexpr int NCHUNK = 16, CHUNK = 64;          // T = 16 chunks of 64

// ---------------- workspace layout (float offsets), extent = 67.24MB (proven safe) ----
constexpr size_t OF_QPRE  = 0;
constexpr size_t OF_KPRE  = 2097152;
constexpr size_t OF_VPRE  = 4194304;
constexpr size_t OF_Q     = 8388608;
constexpr size_t OF_K     = 10485760;
constexpr size_t OF_V     = 12582912;
constexpr size_t OF_G     = 16777216;
constexpr size_t OF_BETA  = 16793600;
constexpr size_t OF_KBART = OF_QPRE;            // 256 chunks * 128 * 64 = 2M
constexpr size_t OF_BT    = OF_KPRE;            // 256 * 64 * 64 = 1M
constexpr size_t OF_CS    = OF_KPRE + 1048576;  // 256 * 64 = 16K
constexpr size_t OF_O     = OF_VPRE;            // 4M
constexpr size_t OF_OO    = OF_Q;               // 4M over q+k (after phase2)
constexpr size_t OF_GV    = OF_V;               // 4M over v (after phase2)

using short8 = __attribute__((ext_vector_type(8))) short;
using f32x4  = __attribute__((ext_vector_type(4))) float;

__device__ inline unsigned short f2bf(float f) {  // RNE fp32->bf16
  unsigned int u = __builtin_bit_cast(unsigned int, f);
  u += 0x7FFFu + ((u >> 16) & 1u);
  return (unsigned short)(u >> 16);
}

// ---------------- bf16-MFMA GEMM: C[M,N](f32) = A[M,K](f32) @ B[K,N](f32) ----------------
// On-the-fly bf16 conversion in staging. Tile 128x128, BK=32, 4 waves (2x2),
// 4x4 frags of 16x16x32 per wave. LDS stride 40 bf16 (80B): fragment reads ~2-way
// (free), B-transpose scatter writes bank-uniform (map n=(l&7)+8j).
__global__ __launch_bounds__(256) void gemm_bf16(const float* __restrict__ A,
                                                 const float* __restrict__ B,
                                                 float* __restrict__ C,
                                                 int M, int N, int K) {
  __shared__ unsigned short As[128 * 40];
  __shared__ unsigned short Bs[128 * 40];
  const int tid = threadIdx.x;
  const int lane = tid & 63;
  const int wid = tid >> 6;
  const int m0 = blockIdx.y * 128, n0 = blockIdx.x * 128;
  const int wm = (wid >> 1) * 64, wn = (wid & 1) * 64;
  const int fr = lane & 15;          // fragment row (A) / col (B)
  const int ko = (lane >> 4) * 8;    // fragment k-offset
  f32x4 acc[4][4] = {};

  const int rb = tid >> 3, kq = (tid & 7) * 4;   // A-stage map
  const int kk = tid >> 3, nb = tid & 7;         // B-stage map

  for (int k0 = 0; k0 < K; k0 += 32) {
    // ---- stage A: 128 rows x 32 k; 8 lanes cover one row's 128B (coalesced) ----
#pragma unroll
    for (int i = 0; i < 4; ++i) {
      int r = rb + 32 * i;
      float4 f = *(const float4*)&A[(size_t)(m0 + r) * K + k0 + kq];
      unsigned short* w = &As[r * 40 + kq];
      w[0] = f2bf(f.x); w[1] = f2bf(f.y); w[2] = f2bf(f.z); w[3] = f2bf(f.w);
    }
    // ---- stage B transposed: BsT[n][kk]; scalar loads, bank-uniform b16 writes ----
    {
      const float* Bp = &B[(size_t)(k0 + kk) * N + n0 + nb];
#pragma unroll
      for (int j = 0; j < 16; ++j) {
        Bs[(nb + 8 * j) * 40 + kk] = f2bf(Bp[8 * j]);
      }
    }
    __syncthreads();
    // ---- fragments + MFMA ----
    short8 a[4], b[4];
#pragma unroll
    for (int mf = 0; mf < 4; ++mf)
      a[mf] = *(const short8*)&As[(wm + mf * 16 + fr) * 40 + ko];
#pragma unroll
    for (int nf = 0; nf < 4; ++nf)
      b[nf] = *(const short8*)&Bs[(wn + nf * 16 + fr) * 40 + ko];
#pragma unroll
    for (int mf = 0; mf < 4; ++mf)
#pragma unroll
      for (int nf = 0; nf < 4; ++nf)
        acc[mf][nf] = __builtin_amdgcn_mfma_f32_16x16x32_bf16(a[mf], b[nf], acc[mf][nf], 0, 0, 0);
    __syncthreads();
  }
  // ---- epilogue: D row=(l>>4)*4+r, col=l&15 (m89-verified) ----
  const int orow = (lane >> 4) * 4;
#pragma unroll
  for (int mf = 0; mf < 4; ++mf)
#pragma unroll
    for (int nf = 0; nf < 4; ++nf)
#pragma unroll
      for (int r = 0; r < 4; ++r)
        C[(size_t)(m0 + wm + mf * 16 + orow + r) * N + n0 + wn + nf * 16 + fr] = acc[mf][nf][r];
}

// ---------------- depthwise causal conv1d (K=4) + silu ----------------
__global__ __launch_bounds__(256) void conv_silu(const float* __restrict__ X,
                                                 const float* __restrict__ W,
                                                 float* __restrict__ Y, int C) {
  int c = blockIdx.x * 256 + threadIdx.x;
  if (c >= C) return;
  int b  = blockIdx.z;
  int t0 = blockIdx.y * 32;
  float4 w = *(const float4*)&W[c * 4];
  const float* xp = X + (size_t)b * Tc * C + c;
  float* yp = Y + (size_t)b * Tc * C + c;
  float x0 = (t0 >= 3) ? xp[(size_t)(t0 - 3) * C] : 0.f;
  float x1 = (t0 >= 2) ? xp[(size_t)(t0 - 2) * C] : 0.f;
  float x2 = (t0 >= 1) ? xp[(size_t)(t0 - 1) * C] : 0.f;
  for (int t = t0; t < t0 + 32; ++t) {
    float x3 = xp[(size_t)t * C];
    float a  = w.x * x0 + w.y * x1 + w.z * x2 + w.w * x3;
    float y  = a / (1.f + __expf(-a));
    yp[(size_t)t * C] = y;
    x0 = x1; x1 = x2; x2 = x3;
  }
}

// ---------------- beta + g_log: one wave per (b,t,h) ----------------
__global__ __launch_bounds__(256) void beta_g_kernel(const float* __restrict__ X,
                                                     const float* __restrict__ Wb,
                                                     const float* __restrict__ Wa,
                                                     const float* __restrict__ A_log,
                                                     const float* __restrict__ dt_bias,
                                                     float* __restrict__ beta,
                                                     float* __restrict__ glog) {
  int w    = blockIdx.x * 4 + (threadIdx.x >> 6);
  int lane = threadIdx.x & 63;
  int h  = w & 7;
  int bt = w >> 3;
  const float* x = X + (size_t)bt * Dc;
  float sb = 0.f, sa = 0.f;
#pragma unroll
  for (int i = 0; i < 16; ++i) {
    int d = lane + 64 * i;
    float xv = x[d];
    sb = fmaf(xv, Wb[d * 8 + h], sb);
    sa = fmaf(xv, Wa[d * 8 + h], sa);
  }
#pragma unroll
  for (int m = 1; m < 64; m <<= 1) {
    sb += __shfl_xor(sb, m);
    sa += __shfl_xor(sa, m);
  }
  if (lane == 0) {
    beta[w] = 1.f / (1.f + expf(-sb));
    float z  = sa + dt_bias[h];
    float sp = (z > 20.f) ? z : log1pf(expf(z));
    glog[w]  = -expf(A_log[h]) * sp;
  }
}

// ---------------- l2norm q (scaled) and k: one wave per (b,t,h) ----------------
__global__ __launch_bounds__(256) void l2norm_qk(float* __restrict__ Q, float* __restrict__ K) {
  int w    = blockIdx.x * 4 + (threadIdx.x >> 6);
  int lane = threadIdx.x & 63;
  int h = w & 7;
  size_t bt = (size_t)(w >> 3);
  float* qp = Q + bt * (Hc * DKc) + h * DKc + lane * 2;
  float* kp = K + bt * (Hc * DKc) + h * DKc + lane * 2;
  float2 q2 = *(float2*)qp;
  float2 k2 = *(float2*)kp;
  float sq = q2.x * q2.x + q2.y * q2.y;
  float sk = k2.x * k2.x + k2.y * k2.y;
#pragma unroll
  for (int m = 1; m < 64; m <<= 1) {
    sq += __shfl_xor(sq, m);
    sk += __shfl_xor(sk, m);
  }
  float rq = rsqrtf(sq + 1e-6f) * QSCALE;
  float rk = rsqrtf(sk + 1e-6f);
  q2.x *= rq; q2.y *= rq;
  k2.x *= rk; k2.y *= rk;
  *(float2*)qp = q2;
  *(float2*)kp = k2;
}

// ---------------- Phase 1: per (bh, chunk) precompute ----------------
__global__ __launch_bounds__(256) void phase1(const float* __restrict__ Q,
                                              const float* __restrict__ K,
                                              float* __restrict__ V,
                                              const float* __restrict__ G,
                                              const float* __restrict__ BETA,
                                              float* __restrict__ KbarT,
                                              float* __restrict__ BTm,
                                              float* __restrict__ CS) {
  constexpr int SK = 68;
  __shared__ float sm[25984];
  float* kcT  = sm;            // [128][68]
  float* qcT  = sm + 8704;     // [128][68]
  float* vld  = sm;            // [64][256] (reuse after barrier)
  float* Amat = sm + 17408;    // [64][65]
  float* Mmat = sm + 21568;    // [64][65]
  float* cs   = sm + 25728;
  float* gam  = sm + 25792;
  float* bet  = sm + 25856;
  float* wk   = sm + 25920;
  const int tid = threadIdx.x;
  const int c = blockIdx.x, bh = blockIdx.y;
  const int b = bh >> 3, h = bh & 7;
  const int t0 = c * CHUNK;
  const size_t cb = (size_t)bh * NCHUNK + c;

  if (tid < 64) {
    cs[tid]  = G[((size_t)(b * Tc + t0 + tid)) * 8 + h];
    bet[tid] = BETA[((size_t)(b * Tc + t0 + tid)) * 8 + h];
  }
  {
    int r = tid >> 2, dq = (tid & 3) * 32;
    const float4* kg = (const float4*)&K[((size_t)(b * Tc + t0 + r)) * 1024 + h * 128 + dq];
    const float4* qg = (const float4*)&Q[((size_t)(b * Tc + t0 + r)) * 1024 + h * 128 + dq];
#pragma unroll
    for (int m = 0; m < 8; ++m) {
      float4 kv = kg[m], qv = qg[m];
      int d = dq + m * 4;
      kcT[(d + 0) * SK + r] = kv.x; kcT[(d + 1) * SK + r] = kv.y;
      kcT[(d + 2) * SK + r] = kv.z; kcT[(d + 3) * SK + r] = kv.w;
      qcT[(d + 0) * SK + r] = qv.x; qcT[(d + 1) * SK + r] = qv.y;
      qcT[(d + 2) * SK + r] = qv.z; qcT[(d + 3) * SK + r] = qv.w;
    }
  }
  __syncthreads();
  if (tid == 0) {
    float a = 0.f;
    for (int i = 0; i < 64; ++i) { a += cs[i]; cs[i] = a; }
  }
  __syncthreads();
  if (tid < 64) {
    float gv_ = __expf(cs[tid]);
    gam[tid] = gv_;
    wk[tid]  = bet[tid] * gv_;
    CS[cb * 64 + tid] = cs[tid];
  }
  for (int e = tid; e < 4096; e += 256) {
    int i = e >> 6, s = e & 63;
    float av = 0.f;
    if (s < i) {
      float acc = 0.f;
      for (int d = 0; d < 128; ++d) acc += kcT[d * SK + i] * kcT[d * SK + s];
      av = bet[i] * __expf(cs[i] - cs[s]) * acc;
    }
    Amat[i * 65 + s] = av;
  }
  for (int e = tid; e < 4096; e += 256) {
    int s = e >> 6, i = e & 63;
    float outv = 0.f;
    if (s <= i) {
      float acc = 0.f;
      for (int d = 0; d < 128; ++d) acc += qcT[d * SK + i] * kcT[d * SK + s];
      outv = __expf(cs[i] - cs[s]) * acc;
    }
    BTm[cb * 4096 + (size_t)s * 64 + i] = outv;
  }
  __syncthreads();
  if (tid < 64) {
    int j = tid;
    for (int i = 0; i < 64; ++i) {
      float m = (i == j) ? 1.f : 0.f;
      for (int s = 0; s < i; ++s) m -= Amat[i * 65 + s] * Mmat[s * 65 + j];
      Mmat[i * 65 + j] = m;
    }
  }
  __syncthreads();
  for (int e = tid; e < 2048; e += 256) {
    int d = e >> 4, i0 = (e & 15) * 4;
    float a0 = 0, a1 = 0, a2 = 0, a3 = 0;
    for (int s = 0; s < 64; ++s) {
      float kv = wk[s] * kcT[d * SK + s];
      a0 = fmaf(Mmat[(i0 + 0) * 65 + s], kv, a0);
      a1 = fmaf(Mmat[(i0 + 1) * 65 + s], kv, a1);
      a2 = fmaf(Mmat[(i0 + 2) * 65 + s], kv, a2);
      a3 = fmaf(Mmat[(i0 + 3) * 65 + s], kv, a3);
    }
    float4 w4 = {a0, a1, a2, a3};
    *(float4*)&KbarT[cb * 8192 + (size_t)d * 64 + i0] = w4;
  }
  __syncthreads();
  {
    int r = tid >> 2, j0 = (tid & 3) * 64;
    const float4* vg = (const float4*)&V[((size_t)(b * Tc + t0 + r)) * 2048 + h * 256 + j0];
#pragma unroll
    for (int m = 0; m < 16; ++m) *(float4*)&vld[r * 256 + j0 + m * 4] = vg[m];
  }
  __syncthreads();
  for (int e = tid; e < 4096; e += 256) {
    int i = e >> 6, j0 = (e & 63) * 4;
    float a0 = 0, a1 = 0, a2 = 0, a3 = 0;
    for (int s = 0; s < 64; ++s) {
      float m_ = Mmat[i * 65 + s] * bet[s];
      float4 vv = *(const float4*)&vld[s * 256 + j0];
      a0 = fmaf(m_, vv.x, a0); a1 = fmaf(m_, vv.y, a1);
      a2 = fmaf(m_, vv.z, a2); a3 = fmaf(m_, vv.w, a3);
    }
    float4 o4 = {a0, a1, a2, a3};
    *(float4*)&V[((size_t)(b * Tc + t0 + i)) * 2048 + h * 256 + j0] = o4;
  }
}

// ---------------- Phase 2: serial-over-chunks, column-parallel ----------------
__global__ __launch_bounds__(256) void phase2(const float* __restrict__ KbarT,
                                              const float* __restrict__ BTm,
                                              const float* __restrict__ CS,
                                              const float* __restrict__ Qp,
                                              const float* __restrict__ Kp,
                                              const float* __restrict__ VBAR,
                                              float* __restrict__ O) {
  __shared__ float S[128 * 32];
  __shared__ float KbT[128 * 68];
  __shared__ float QgL[128 * 68];
  __shared__ float K2c[64 * 128];
  __shared__ float BcT[64 * 68];
  __shared__ float u[64 * 32];
  __shared__ float csL[64], rs[64], gamL[64];
  const int tid = threadIdx.x;
  const int jb = blockIdx.x, bh = blockIdx.y;
  const int b = bh >> 3, h = bh & 7;
  const int ti = tid & 15, tj = tid >> 4;
  const int i0 = ti * 4, jj0 = tj * 2;
  const int td = tid & 31, d0 = td * 4;
  const int jj5 = (tid >> 5) * 4;
  for (int e = tid; e < 4096; e += 256) S[e] = 0.f;

  for (int c = 0; c < NCHUNK; ++c) {
    const size_t cb = (size_t)bh * NCHUNK + c;
    const int t0 = c * CHUNK;
    __syncthreads();
    if (tid < 64) csL[tid] = CS[cb * 64 + tid];
    {
      const float4* g4 = (const float4*)(KbarT + cb * 8192);
      for (int e = tid; e < 2048; e += 256) {
        int d = e >> 4, i4 = (e & 15) * 4;
        *(float4*)&KbT[d * 68 + i4] = g4[e];
      }
      int r = tid >> 2, dq = (tid & 3) * 32;
      const float4* qg4 = (const float4*)&Qp[((size_t)(b * Tc + t0 + r)) * 1024 + h * 128 + dq];
#pragma unroll
      for (int m = 0; m < 8; ++m) {
        float4 f = qg4[m];
        int d = dq + m * 4;
        QgL[(d + 0) * 68 + r] = f.x; QgL[(d + 1) * 68 + r] = f.y;
        QgL[(d + 2) * 68 + r] = f.z; QgL[(d + 3) * 68 + r] = f.w;
      }
      for (int e = tid; e < 2048; e += 256) {
        int s = e >> 5, d4 = (e & 31) * 4;
        float4 f = *(const float4*)&Kp[((size_t)(b * Tc + t0 + s)) * 1024 + h * 128 + d4];
        *(float4*)&K2c[s * 128 + d4] = f;
      }
      const float4* b4 = (const float4*)(BTm + cb * 4096);
      for (int e = tid; e < 1024; e += 256) {
        int s = e >> 4, i4 = (e & 15) * 4;
        *(float4*)&BcT[s * 68 + i4] = b4[e];
      }
    }
    __syncthreads();
    if (tid < 64) {
      gamL[tid] = __expf(csL[tid]);
      rs[tid]   = __expf(csL[63] - csL[tid]);
    }
    float ua[4][2] = {}, ra[4][2] = {};
    for (int d = 0; d < 128; ++d) {
      float4 kb = *(const float4*)&KbT[d * 68 + i0];
      float4 qg = *(const float4*)&QgL[d * 68 + i0];
      float s0 = S[d * 32 + jj0];
      float s1 = S[d * 32 + jj0 + 1];
      ua[0][0] = fmaf(kb.x, s0, ua[0][0]); ua[0][1] = fmaf(kb.x, s1, ua[0][1]);
      ua[1][0] = fmaf(kb.y, s0, ua[1][0]); ua[1][1] = fmaf(kb.y, s1, ua[1][1]);
      ua[2][0] = fmaf(kb.z, s0, ua[2][0]); ua[2][1] = fmaf(kb.z, s1, ua[2][1]);
      ua[3][0] = fmaf(kb.w, s0, ua[3][0]); ua[3][1] = fmaf(kb.w, s1, ua[3][1]);
      ra[0][0] = fmaf(qg.x, s0, ra[0][0]); ra[0][1] = fmaf(qg.x, s1, ra[0][1]);
      ra[1][0] = fmaf(qg.y, s0, ra[1][0]); ra[1][1] = fmaf(qg.y, s1, ra[1][1]);
      ra[2][0] = fmaf(qg.z, s0, ra[2][0]); ra[2][1] = fmaf(qg.z, s1, ra[2][1]);
      ra[3][0] = fmaf(qg.w, s0, ra[3][0]); ra[3][1] = fmaf(qg.w, s1, ra[3][1]);
    }
#pragma unroll
    for (int r = 0; r < 4; ++r)
#pragma unroll
      for (int cc = 0; cc < 2; ++cc) {
        int i = i0 + r, jj = jj0 + cc;
        float vb = VBAR[((size_t)(b * Tc + t0 + i)) * 2048 + h * 256 + jb * 32 + jj];
        u[i * 32 + jj] = vb - ua[r][cc];
      }
    __syncthreads();
    float ba[4][2] = {};
    for (int s = 0; s < 64; ++s) {
      float4 bt = *(const float4*)&BcT[s * 68 + i0];
      float u0 = u[s * 32 + jj0], u1 = u[s * 32 + jj0 + 1];
      ba[0][0] = fmaf(bt.x, u0, ba[0][0]); ba[0][1] = fmaf(bt.x, u1, ba[0][1]);
      ba[1][0] = fmaf(bt.y, u0, ba[1][0]); ba[1][1] = fmaf(bt.y, u1, ba[1][1]);
      ba[2][0] = fmaf(bt.z, u0, ba[2][0]); ba[2][1] = fmaf(bt.z, u1, ba[2][1]);
      ba[3][0] = fmaf(bt.w, u0, ba[3][0]); ba[3][1] = fmaf(bt.w, u1, ba[3][1]);
    }
#pragma unroll
    for (int r = 0; r < 4; ++r)
#pragma unroll
      for (int cc = 0; cc < 2; ++cc) {
        int i = i0 + r, jj = jj0 + cc;
        O[((size_t)(b * Tc + t0 + i)) * 2048 + h * 256 + jb * 32 + jj] =
            gamL[i] * ra[r][cc] + ba[r][cc];
      }
    float sa[4][4] = {};
    for (int s = 0; s < 64; ++s) {
      float4 k2v = *(const float4*)&K2c[s * 128 + d0];
      float4 uv  = *(const float4*)&u[s * 32 + jj5];
      float rsv = rs[s];
      float u0 = uv.x * rsv, u1 = uv.y * rsv, u2 = uv.z * rsv, u3 = uv.w * rsv;
      sa[0][0] = fmaf(k2v.x, u0, sa[0][0]); sa[0][1] = fmaf(k2v.x, u1, sa[0][1]);
      sa[0][2] = fmaf(k2v.x, u2, sa[0][2]); sa[0][3] = fmaf(k2v.x, u3, sa[0][3]);
      sa[1][0] = fmaf(k2v.y, u0, sa[1][0]); sa[1][1] = fmaf(k2v.y, u1, sa[1][1]);
      sa[1][2] = fmaf(k2v.y, u2, sa[1][2]); sa[1][3] = fmaf(k2v.y, u3, sa[1][3]);
      sa[2][0] = fmaf(k2v.z, u0, sa[2][0]); sa[2][1] = fmaf(k2v.z, u1, sa[2][1]);
      sa[2][2] = fmaf(k2v.z, u2, sa[2][2]); sa[2][3] = fmaf(k2v.z, u3, sa[2][3]);
      sa[3][0] = fmaf(k2v.w, u0, sa[3][0]); sa[3][1] = fmaf(k2v.w, u1, sa[3][1]);
      sa[3][2] = fmaf(k2v.w, u2, sa[3][2]); sa[3][3] = fmaf(k2v.w, u3, sa[3][3]);
    }
    float gC = gamL[63];
#pragma unroll
    for (int r = 0; r < 4; ++r)
#pragma unroll
      for (int cc = 0; cc < 4; ++cc) {
        int idx = (d0 + r) * 32 + jj5 + cc;
        S[idx] = fmaf(gC, S[idx], sa[r][cc]);
      }
  }
}

// ---------------- fused gated RMSNorm ----------------
__global__ __launch_bounds__(256) void gated_rmsnorm(const float* __restrict__ O,
                                                     const float* __restrict__ GV,
                                                     const float* __restrict__ NW,
                                                     float* __restrict__ OO) {
  int w    = blockIdx.x * 4 + (threadIdx.x >> 6);
  int lane = threadIdx.x & 63;
  size_t base = (size_t)w * DVc;
  float4 o4 = *(const float4*)&O[base + lane * 4];
  float ss = o4.x * o4.x + o4.y * o4.y + o4.z * o4.z + o4.w * o4.w;
#pragma unroll
  for (int m = 1; m < 64; m <<= 1) ss += __shfl_xor(ss, m);
  float r = rsqrtf(ss * (1.f / 256.f) + 1e-5f);
  float4 g4 = *(const float4*)&GV[base + lane * 4];
  float4 w4 = *(const float4*)&NW[lane * 4];
  float4 out;
  out.x = o4.x * r * w4.x * (g4.x / (1.f + __expf(-g4.x)));
  out.y = o4.y * r * w4.y * (g4.y / (1.f + __expf(-g4.y)));
  out.z = o4.z * r * w4.z * (g4.z / (1.f + __expf(-g4.z)));
  out.w = o4.w * r * w4.w * (g4.w / (1.f + __expf(-g4.w)));
  *(float4*)&OO[base + lane * 4] = out;
}

// ---------------- launcher ----------------
extern "C" void kernel_launch(void* const* d_in, const int* in_sizes, int n_in,
                              void* d_out, int out_size, void* d_ws, size_t ws_size,
                              hipStream_t stream) {
  const float* x       = (const float*)d_in[0];
  const float* Wq      = (const float*)d_in[1];
  const float* Wk      = (const float*)d_in[2];
  const float* Wv      = (const float*)d_in[3];
  const float* conv_q  = (const float*)d_in[4];
  const float* conv_k  = (const float*)d_in[5];
  const float* conv_v  = (const float*)d_in[6];
  const float* Wb      = (const float*)d_in[7];
  const float* Wa      = (const float*)d_in[8];
  const float* A_log   = (const float*)d_in[9];
  const float* dt_bias = (const float*)d_in[10];
  const float* Wg      = (const float*)d_in[11];
  const float* norm_w  = (const float*)d_in[12];
  const float* Wo      = (const float*)d_in[13];
  float* out = (float*)d_out;
  float* ws  = (float*)d_ws;

  float* qpre  = ws + OF_QPRE;
  float* kpre  = ws + OF_KPRE;
  float* vpre  = ws + OF_VPRE;
  float* q     = ws + OF_Q;
  float* k     = ws + OF_K;
  float* v     = ws + OF_V;
  float* glog  = ws + OF_G;
  float* beta  = ws + OF_BETA;
  float* KbarT = ws + OF_KBART;
  float* BTm   = ws + OF_BT;
  float* CSb   = ws + OF_CS;
  float* o     = ws + OF_O;
  float* oo    = ws + OF_OO;
  float* gv    = ws + OF_GV;

  dim3 blk(256);

  // projections (bf16 MFMA)
  gemm_bf16<<<dim3(1024 / 128, BT_ROWS / 128), blk, 0, stream>>>(x, Wq, qpre, BT_ROWS, 1024, 1024);
  gemm_bf16<<<dim3(1024 / 128, BT_ROWS / 128), blk, 0, stream>>>(x, Wk, kpre, BT_ROWS, 1024, 1024);
  gemm_bf16<<<dim3(2048 / 128, BT_ROWS / 128), blk, 0, stream>>>(x, Wv, vpre, BT_ROWS, 2048, 1024);

  // beta + log-decay (fp32 — feeds exponentials)
  beta_g_kernel<<<dim3(BT_ROWS * Hc / 4), blk, 0, stream>>>(x, Wb, Wa, A_log, dt_bias, beta, glog);

  // causal conv + silu
  conv_silu<<<dim3(1024 / 256, Tc / 32, Bc), blk, 0, stream>>>(qpre, conv_q, q, 1024);
  conv_silu<<<dim3(1024 / 256, Tc / 32, Bc), blk, 0, stream>>>(kpre, conv_k, k, 1024);
  conv_silu<<<dim3(2048 / 256, Tc / 32, Bc), blk, 0, stream>>>(vpre, conv_v, v, 2048);

  // l2norm q (scaled) and k
  l2norm_qk<<<dim3(BT_ROWS * Hc / 4), blk, 0, stream>>>(q, k);

  // chunked delta rule
  phase1<<<dim3(NCHUNK, Bc * Hc), blk, 0, stream>>>(q, k, v, glog, beta, KbarT, BTm, CSb);
  phase2<<<dim3(8, Bc * Hc), blk, 0, stream>>>(KbarT, BTm, CSb, q, k, v, o);

  // gv = x @ Wg (into v slot, dead after phase2)
  gemm_bf16<<<dim3(2048 / 128, BT_ROWS / 128), blk, 0, stream>>>(x, Wg, gv, BT_ROWS, 2048, 1024);

  // gated rmsnorm (oo over q+k, dead after phase2)
  gated_rmsnorm<<<dim3(BT_ROWS * Hc / 4), blk, 0, stream>>>(o, gv, norm_w, oo);

  // out = oo @ Wo
  gemm_bf16<<<dim3(1024 / 128, BT_ROWS / 128), blk, 0, stream>>>(oo, Wo, out, BT_ROWS, 1024, 2048);
}

// Round 6
// 714.846 us; speedup vs baseline: 2.9156x; 1.1734x over previous
//
#include <hip/hip_runtime.h>
#include <hip/hip_bf16.h>
#include <math.h>

// Problem dims (fixed by reference)
constexpr int Bc = 2, Tc = 1024, Dc = 1024, Hc = 8, DKc = 128, DVc = 256;
constexpr int BT_ROWS = Bc * Tc;                // 2048 rows
constexpr float QSCALE = 0.08838834764831845f;  // 128^-0.5
constexpr int NCHUNK = 16, CHUNK = 64;          // T = 16 chunks of 64

// ---------------- workspace layout (float offsets), extent = 67.24MB (proven safe) ----
constexpr size_t OF_QPRE  = 0;
constexpr size_t OF_KPRE  = 2097152;
constexpr size_t OF_VPRE  = 4194304;
constexpr size_t OF_Q     = 8388608;
constexpr size_t OF_K     = 10485760;
constexpr size_t OF_V     = 12582912;
constexpr size_t OF_G     = 16777216;
constexpr size_t OF_BETA  = 16793600;
constexpr size_t OF_KBAR  = OF_QPRE;            // 256 chunks * 64 * 128 = 2M (i-major)
constexpr size_t OF_BT    = OF_KPRE;            // 256 * 64 * 64 = 1M
constexpr size_t OF_CS    = OF_KPRE + 1048576;  // 256 * 64 = 16K
constexpr size_t OF_O     = OF_VPRE;            // 4M
constexpr size_t OF_OO    = OF_Q;               // 4M over q+k (after phase2)
constexpr size_t OF_GV    = OF_V;               // 4M over v (after phase2)

using short8 = __attribute__((ext_vector_type(8))) short;
using f32x4  = __attribute__((ext_vector_type(4))) float;

__device__ inline unsigned short f2bf(float f) {  // RNE fp32->bf16
  unsigned int u = __builtin_bit_cast(unsigned int, f);
  u += 0x7FFFu + ((u >> 16) & 1u);
  return (unsigned short)(u >> 16);
}

// async global->LDS 16B copy (dest wave-uniform base + lane*16; src per-lane)
__device__ inline void gload16(const void* g, void* l) {
  __builtin_amdgcn_global_load_lds(
      (const __attribute__((address_space(1))) unsigned int*)g,
      (__attribute__((address_space(3))) unsigned int*)l, 16, 0, 0);
}

// ---------------- bf16-MFMA GEMM (proven R4): C f32 = A f32 @ B f32 ----------------
__global__ __launch_bounds__(256) void gemm_bf16(const float* __restrict__ A,
                                                 const float* __restrict__ B,
                                                 float* __restrict__ C,
                                                 int M, int N, int K) {
  __shared__ unsigned short As[128 * 40];
  __shared__ unsigned short Bs[128 * 40];
  const int tid = threadIdx.x;
  const int lane = tid & 63;
  const int wid = tid >> 6;
  const int m0 = blockIdx.y * 128, n0 = blockIdx.x * 128;
  const int wm = (wid >> 1) * 64, wn = (wid & 1) * 64;
  const int fr = lane & 15;
  const int ko = (lane >> 4) * 8;
  f32x4 acc[4][4] = {};

  const int rb = tid >> 3, kq = (tid & 7) * 4;
  const int kk = tid >> 3, nb = tid & 7;

  for (int k0 = 0; k0 < K; k0 += 32) {
#pragma unroll
    for (int i = 0; i < 4; ++i) {
      int r = rb + 32 * i;
      float4 f = *(const float4*)&A[(size_t)(m0 + r) * K + k0 + kq];
      unsigned short* w = &As[r * 40 + kq];
      w[0] = f2bf(f.x); w[1] = f2bf(f.y); w[2] = f2bf(f.z); w[3] = f2bf(f.w);
    }
    {
      const float* Bp = &B[(size_t)(k0 + kk) * N + n0 + nb];
#pragma unroll
      for (int j = 0; j < 16; ++j) {
        Bs[(nb + 8 * j) * 40 + kk] = f2bf(Bp[8 * j]);
      }
    }
    __syncthreads();
    short8 a[4], b[4];
#pragma unroll
    for (int mf = 0; mf < 4; ++mf)
      a[mf] = *(const short8*)&As[(wm + mf * 16 + fr) * 40 + ko];
#pragma unroll
    for (int nf = 0; nf < 4; ++nf)
      b[nf] = *(const short8*)&Bs[(wn + nf * 16 + fr) * 40 + ko];
#pragma unroll
    for (int mf = 0; mf < 4; ++mf)
#pragma unroll
      for (int nf = 0; nf < 4; ++nf)
        acc[mf][nf] = __builtin_amdgcn_mfma_f32_16x16x32_bf16(a[mf], b[nf], acc[mf][nf], 0, 0, 0);
    __syncthreads();
  }
  const int orow = (lane >> 4) * 4;
#pragma unroll
  for (int mf = 0; mf < 4; ++mf)
#pragma unroll
    for (int nf = 0; nf < 4; ++nf)
#pragma unroll
      for (int r = 0; r < 4; ++r)
        C[(size_t)(m0 + wm + mf * 16 + orow + r) * N + n0 + wn + nf * 16 + fr] = acc[mf][nf][r];
}

// ---------------- depthwise causal conv1d (K=4) + silu ----------------
__global__ __launch_bounds__(256) void conv_silu(const float* __restrict__ X,
                                                 const float* __restrict__ W,
                                                 float* __restrict__ Y, int C) {
  int c = blockIdx.x * 256 + threadIdx.x;
  if (c >= C) return;
  int b  = blockIdx.z;
  int t0 = blockIdx.y * 32;
  float4 w = *(const float4*)&W[c * 4];
  const float* xp = X + (size_t)b * Tc * C + c;
  float* yp = Y + (size_t)b * Tc * C + c;
  float x0 = (t0 >= 3) ? xp[(size_t)(t0 - 3) * C] : 0.f;
  float x1 = (t0 >= 2) ? xp[(size_t)(t0 - 2) * C] : 0.f;
  float x2 = (t0 >= 1) ? xp[(size_t)(t0 - 1) * C] : 0.f;
  for (int t = t0; t < t0 + 32; ++t) {
    float x3 = xp[(size_t)t * C];
    float a  = w.x * x0 + w.y * x1 + w.z * x2 + w.w * x3;
    float y  = a / (1.f + __expf(-a));
    yp[(size_t)t * C] = y;
    x0 = x1; x1 = x2; x2 = x3;
  }
}

// ---------------- beta + g_log: one wave per (b,t,h) ----------------
__global__ __launch_bounds__(256) void beta_g_kernel(const float* __restrict__ X,
                                                     const float* __restrict__ Wb,
                                                     const float* __restrict__ Wa,
                                                     const float* __restrict__ A_log,
                                                     const float* __restrict__ dt_bias,
                                                     float* __restrict__ beta,
                                                     float* __restrict__ glog) {
  int w    = blockIdx.x * 4 + (threadIdx.x >> 6);
  int lane = threadIdx.x & 63;
  int h  = w & 7;
  int bt = w >> 3;
  const float* x = X + (size_t)bt * Dc;
  float sb = 0.f, sa = 0.f;
#pragma unroll
  for (int i = 0; i < 16; ++i) {
    int d = lane + 64 * i;
    float xv = x[d];
    sb = fmaf(xv, Wb[d * 8 + h], sb);
    sa = fmaf(xv, Wa[d * 8 + h], sa);
  }
#pragma unroll
  for (int m = 1; m < 64; m <<= 1) {
    sb += __shfl_xor(sb, m);
    sa += __shfl_xor(sa, m);
  }
  if (lane == 0) {
    beta[w] = 1.f / (1.f + expf(-sb));
    float z  = sa + dt_bias[h];
    float sp = (z > 20.f) ? z : log1pf(expf(z));
    glog[w]  = -expf(A_log[h]) * sp;
  }
}

// ---------------- l2norm q (scaled) and k: one wave per (b,t,h) ----------------
__global__ __launch_bounds__(256) void l2norm_qk(float* __restrict__ Q, float* __restrict__ K) {
  int w    = blockIdx.x * 4 + (threadIdx.x >> 6);
  int lane = threadIdx.x & 63;
  int h = w & 7;
  size_t bt = (size_t)(w >> 3);
  float* qp = Q + bt * (Hc * DKc) + h * DKc + lane * 2;
  float* kp = K + bt * (Hc * DKc) + h * DKc + lane * 2;
  float2 q2 = *(float2*)qp;
  float2 k2 = *(float2*)kp;
  float sq = q2.x * q2.x + q2.y * q2.y;
  float sk = k2.x * k2.x + k2.y * k2.y;
#pragma unroll
  for (int m = 1; m < 64; m <<= 1) {
    sq += __shfl_xor(sq, m);
    sk += __shfl_xor(sk, m);
  }
  float rq = rsqrtf(sq + 1e-6f) * QSCALE;
  float rk = rsqrtf(sk + 1e-6f);
  q2.x *= rq; q2.y *= rq;
  k2.x *= rk; k2.y *= rk;
  *(float2*)qp = q2;
  *(float2*)kp = k2;
}

// ---------------- Phase 1: per (bh, chunk) precompute ----------------
// Outputs: Kbar (i-major [i][d]), BT [s][i], vbar (in-place V), CS.
__global__ __launch_bounds__(256) void phase1(const float* __restrict__ Q,
                                              const float* __restrict__ K,
                                              float* __restrict__ V,
                                              const float* __restrict__ G,
                                              const float* __restrict__ BETA,
                                              float* __restrict__ Kbar,
                                              float* __restrict__ BTm,
                                              float* __restrict__ CS) {
  constexpr int SK = 68;
  __shared__ float sm[25984];
  float* kcT  = sm;            // [128][68]
  float* qcT  = sm + 8704;     // [128][68]
  float* vld  = sm;            // [64][256] (reuse after barrier)
  float* Amat = sm + 17408;    // [64][65]
  float* Mmat = sm + 21568;    // [64][65]
  float* cs   = sm + 25728;
  float* bet  = sm + 25856;
  float* wk   = sm + 25920;
  const int tid = threadIdx.x;
  const int c = blockIdx.x, bh = blockIdx.y;
  const int b = bh >> 3, h = bh & 7;
  const int t0 = c * CHUNK;
  const size_t cb = (size_t)bh * NCHUNK + c;

  if (tid < 64) {
    cs[tid]  = G[((size_t)(b * Tc + t0 + tid)) * 8 + h];
    bet[tid] = BETA[((size_t)(b * Tc + t0 + tid)) * 8 + h];
  }
  {
    int r = tid >> 2, dq = (tid & 3) * 32;
    const float4* kg = (const float4*)&K[((size_t)(b * Tc + t0 + r)) * 1024 + h * 128 + dq];
    const float4* qg = (const float4*)&Q[((size_t)(b * Tc + t0 + r)) * 1024 + h * 128 + dq];
#pragma unroll
    for (int m = 0; m < 8; ++m) {
      float4 kv = kg[m], qv = qg[m];
      int d = dq + m * 4;
      kcT[(d + 0) * SK + r] = kv.x; kcT[(d + 1) * SK + r] = kv.y;
      kcT[(d + 2) * SK + r] = kv.z; kcT[(d + 3) * SK + r] = kv.w;
      qcT[(d + 0) * SK + r] = qv.x; qcT[(d + 1) * SK + r] = qv.y;
      qcT[(d + 2) * SK + r] = qv.z; qcT[(d + 3) * SK + r] = qv.w;
    }
  }
  __syncthreads();
  if (tid == 0) {
    float a = 0.f;
    for (int i = 0; i < 64; ++i) { a += cs[i]; cs[i] = a; }
  }
  __syncthreads();
  if (tid < 64) {
    float gv_ = __expf(cs[tid]);
    wk[tid]  = bet[tid] * gv_;
    CS[cb * 64 + tid] = cs[tid];
  }
  for (int e = tid; e < 4096; e += 256) {
    int i = e >> 6, s = e & 63;
    float av = 0.f;
    if (s < i) {
      float acc = 0.f;
      for (int d = 0; d < 128; ++d) acc += kcT[d * SK + i] * kcT[d * SK + s];
      av = bet[i] * __expf(cs[i] - cs[s]) * acc;
    }
    Amat[i * 65 + s] = av;
  }
  for (int e = tid; e < 4096; e += 256) {
    int s = e >> 6, i = e & 63;
    float outv = 0.f;
    if (s <= i) {
      float acc = 0.f;
      for (int d = 0; d < 128; ++d) acc += qcT[d * SK + i] * kcT[d * SK + s];
      outv = __expf(cs[i] - cs[s]) * acc;
    }
    BTm[cb * 4096 + (size_t)s * 64 + i] = outv;
  }
  __syncthreads();
  if (tid < 64) {
    int j = tid;
    for (int i = 0; i < 64; ++i) {
      float m = (i == j) ? 1.f : 0.f;
      for (int s = 0; s < i; ++s) m -= Amat[i * 65 + s] * Mmat[s * 65 + j];
      Mmat[i * 65 + j] = m;
    }
  }
  __syncthreads();
  // Kbar i-major: Kbar[i][d] = sum_s M[i][s]*beta_s*gamma_s*K[s][d]
  for (int e = tid; e < 2048; e += 256) {
    int i = e & 63, d0 = ((e >> 6) & 31) * 4;
    float a0 = 0, a1 = 0, a2 = 0, a3 = 0;
#pragma unroll 4
    for (int s = 0; s < 64; ++s) {
      float m_ = Mmat[i * 65 + s] * wk[s];
      a0 = fmaf(m_, kcT[(d0 + 0) * SK + s], a0);
      a1 = fmaf(m_, kcT[(d0 + 1) * SK + s], a1);
      a2 = fmaf(m_, kcT[(d0 + 2) * SK + s], a2);
      a3 = fmaf(m_, kcT[(d0 + 3) * SK + s], a3);
    }
    float4 w4 = {a0, a1, a2, a3};
    *(float4*)&Kbar[cb * 8192 + (size_t)i * 128 + d0] = w4;
  }
  __syncthreads();
  {
    int r = tid >> 2, j0 = (tid & 3) * 64;
    const float4* vg = (const float4*)&V[((size_t)(b * Tc + t0 + r)) * 2048 + h * 256 + j0];
#pragma unroll
    for (int m = 0; m < 16; ++m) *(float4*)&vld[r * 256 + j0 + m * 4] = vg[m];
  }
  __syncthreads();
  for (int e = tid; e < 4096; e += 256) {
    int i = e >> 6, j0 = (e & 63) * 4;
    float a0 = 0, a1 = 0, a2 = 0, a3 = 0;
    for (int s = 0; s < 64; ++s) {
      float m_ = Mmat[i * 65 + s] * bet[s];
      float4 vv = *(const float4*)&vld[s * 256 + j0];
      a0 = fmaf(m_, vv.x, a0); a1 = fmaf(m_, vv.y, a1);
      a2 = fmaf(m_, vv.z, a2); a3 = fmaf(m_, vv.w, a3);
    }
    float4 o4 = {a0, a1, a2, a3};
    *(float4*)&V[((size_t)(b * Tc + t0 + i)) * 2048 + h * 256 + j0] = o4;
  }
}

// ---------------- Phase 2: serial-over-chunks, column-parallel ----------------
// Grid (16 col-blocks, 16 bh). Block owns 16 value-cols; S[16][128] ([j][d]) in LDS.
// Per chunk: u = vbar - Kbar@S ; o = gam.*(qc@S) + B@u ; S = gC*S + K2^T@(rs.*u)
// All staging linear via global_load_lds(16B); Kb/qc XOR-swizzled at the SOURCE
// (byte ^= (row&7)<<4) so lane-varies-row ds_read_b128 is bank-spread (T2/m173).
__global__ __launch_bounds__(256) void phase2(const float* __restrict__ KbarG,
                                              const float* __restrict__ BTmG,
                                              const float* __restrict__ CS,
                                              const float* __restrict__ Qp,
                                              const float* __restrict__ Kp,
                                              const float* __restrict__ VBAR,
                                              float* __restrict__ O) {
  __shared__ float S[16 * 132];     // [j][d], pad 132
  __shared__ float KbL[64 * 128];   // [i][d], src-swizzled
  __shared__ float qcL[64 * 128];   // [i][d], src-swizzled
  __shared__ float K2L[64 * 128];   // [s][d], linear
  __shared__ float BcL[64 * 64];    // [s][i], linear
  __shared__ float uL[64 * 20];     // [s][j], pad 20
  __shared__ float csL[64], rsL[64], gamL[64];
  const int tid = threadIdx.x;
  const int l = tid & 63, w = tid >> 6;
  const int jb = blockIdx.x, bh = blockIdx.y;
  const int b = bh >> 3, h = bh & 7;
  const int i = l;                   // u/R2/o row owned by this lane
  const int j0 = w * 4;              // 4 cols per thread
  const int swzi = (i & 7) << 2;     // float-index XOR for Kb/qc reads
  const int d0u = (tid & 31) * 4;    // S-update d-block
  const int jq = tid >> 5;           // S-update j-pair (0..7)
  const size_t colbase = (size_t)h * 256 + jb * 16;

  for (int e = tid; e < 16 * 132; e += 256) S[e] = 0.f;

  for (int c = 0; c < NCHUNK; ++c) {
    const size_t cb = (size_t)bh * NCHUNK + c;
    const int bT0 = b * Tc + c * CHUNK;
    __syncthreads();   // prev chunk compute done before restaging
    // ---- stage (all global_load_lds, dest linear, Kb/qc src pre-swizzled) ----
    if (tid < 64) csL[tid] = CS[cb * 64 + tid];
    {
      const char* kbg = (const char*)(KbarG + cb * 8192);   // 8192 floats/chunk
#pragma unroll
      for (int ic = 0; ic < 8; ++ic) {
        int ch = ic * 4 + w;               // 1KB chunk, 0..31 (2 rows each)
        int row = 2 * ch + (l >> 5);
        int inrow = (l & 31) * 16;
        int swz = inrow ^ ((row & 7) << 4);
        gload16(kbg + row * 512 + swz, (char*)KbL + ch * 1024);
        gload16((const char*)(Qp + ((size_t)(bT0 + row)) * 1024 + h * 128) + swz,
                (char*)qcL + ch * 1024);
        gload16((const char*)(Kp + ((size_t)(bT0 + row)) * 1024 + h * 128) + inrow,
                (char*)K2L + ch * 1024);
      }
      const char* btg = (const char*)(BTmG + cb * 4096);    // 4096 floats/chunk (FIXED)
#pragma unroll
      for (int ic = 0; ic < 4; ++ic) {
        int ch = ic * 4 + w;
        gload16(btg + ch * 1024 + l * 16, (char*)BcL + ch * 1024);
      }
    }
    __syncthreads();   // drains vmcnt (loads) + lgkm
    if (tid < 64) {
      gamL[tid] = __expf(csL[tid]);
      rsL[tid]  = __expf(csL[63] - csL[tid]);
    }
    // ---- u = vbar - Kb@S ; R2 = qc@S  (lane=row i, 4 cols) ----
    float ua[4] = {}, ra[4] = {};
#pragma unroll 4
    for (int d = 0; d < 128; d += 4) {
      int ds = d ^ swzi;
      float4 kb = *(const float4*)&KbL[i * 128 + ds];
      float4 qg = *(const float4*)&qcL[i * 128 + ds];
#pragma unroll
      for (int jj = 0; jj < 4; ++jj) {
        float4 s4 = *(const float4*)&S[(j0 + jj) * 132 + d];
        ua[jj] = fmaf(kb.x, s4.x, fmaf(kb.y, s4.y, fmaf(kb.z, s4.z, fmaf(kb.w, s4.w, ua[jj]))));
        ra[jj] = fmaf(qg.x, s4.x, fmaf(qg.y, s4.y, fmaf(qg.z, s4.z, fmaf(qg.w, s4.w, ra[jj]))));
      }
    }
    float4 vb = *(const float4*)&VBAR[((size_t)(bT0 + i)) * 2048 + colbase + j0];
    float4 uf = {vb.x - ua[0], vb.y - ua[1], vb.z - ua[2], vb.w - ua[3]};
    *(float4*)&uL[i * 20 + j0] = uf;
    __syncthreads();
    // ---- o = gam_i*(qc@S) + B@u ----
    float ba[4] = {};
#pragma unroll 4
    for (int s = 0; s < 64; ++s) {
      float bv = BcL[s * 64 + i];
      float4 u4 = *(const float4*)&uL[s * 20 + j0];
      ba[0] = fmaf(bv, u4.x, ba[0]); ba[1] = fmaf(bv, u4.y, ba[1]);
      ba[2] = fmaf(bv, u4.z, ba[2]); ba[3] = fmaf(bv, u4.w, ba[3]);
    }
    float gi = gamL[i];
    float4 o4 = {gi * ra[0] + ba[0], gi * ra[1] + ba[1],
                 gi * ra[2] + ba[2], gi * ra[3] + ba[3]};
    *(float4*)&O[((size_t)(bT0 + i)) * 2048 + colbase + j0] = o4;
    // ---- S[j][d] = gC*S + sum_s K2[s][d]*(u[s][j]*rs[s]) ----
    float sa[2][4] = {};
#pragma unroll 4
    for (int s = 0; s < 64; ++s) {
      float4 k2 = *(const float4*)&K2L[s * 128 + d0u];
      float rv = rsL[s];
      float u0 = uL[s * 20 + 2 * jq] * rv;
      float u1 = uL[s * 20 + 2 * jq + 1] * rv;
      sa[0][0] = fmaf(k2.x, u0, sa[0][0]); sa[0][1] = fmaf(k2.y, u0, sa[0][1]);
      sa[0][2] = fmaf(k2.z, u0, sa[0][2]); sa[0][3] = fmaf(k2.w, u0, sa[0][3]);
      sa[1][0] = fmaf(k2.x, u1, sa[1][0]); sa[1][1] = fmaf(k2.y, u1, sa[1][1]);
      sa[1][2] = fmaf(k2.z, u1, sa[1][2]); sa[1][3] = fmaf(k2.w, u1, sa[1][3]);
    }
    float gC = gamL[63];
#pragma unroll
    for (int jj = 0; jj < 2; ++jj) {
      float4 sv = *(const float4*)&S[(2 * jq + jj) * 132 + d0u];
      sv.x = fmaf(gC, sv.x, sa[jj][0]); sv.y = fmaf(gC, sv.y, sa[jj][1]);
      sv.z = fmaf(gC, sv.z, sa[jj][2]); sv.w = fmaf(gC, sv.w, sa[jj][3]);
      *(float4*)&S[(2 * jq + jj) * 132 + d0u] = sv;
    }
  }
}

// ---------------- fused gated RMSNorm ----------------
__global__ __launch_bounds__(256) void gated_rmsnorm(const float* __restrict__ O,
                                                     const float* __restrict__ GV,
                                                     const float* __restrict__ NW,
                                                     float* __restrict__ OO) {
  int w    = blockIdx.x * 4 + (threadIdx.x >> 6);
  int lane = threadIdx.x & 63;
  size_t base = (size_t)w * DVc;
  float4 o4 = *(const float4*)&O[base + lane * 4];
  float ss = o4.x * o4.x + o4.y * o4.y + o4.z * o4.z + o4.w * o4.w;
#pragma unroll
  for (int m = 1; m < 64; m <<= 1) ss += __shfl_xor(ss, m);
  float r = rsqrtf(ss * (1.f / 256.f) + 1e-5f);
  float4 g4 = *(const float4*)&GV[base + lane * 4];
  float4 w4 = *(const float4*)&NW[lane * 4];
  float4 out;
  out.x = o4.x * r * w4.x * (g4.x / (1.f + __expf(-g4.x)));
  out.y = o4.y * r * w4.y * (g4.y / (1.f + __expf(-g4.y)));
  out.z = o4.z * r * w4.z * (g4.z / (1.f + __expf(-g4.z)));
  out.w = o4.w * r * w4.w * (g4.w / (1.f + __expf(-g4.w)));
  *(float4*)&OO[base + lane * 4] = out;
}

// ---------------- launcher ----------------
extern "C" void kernel_launch(void* const* d_in, const int* in_sizes, int n_in,
                              void* d_out, int out_size, void* d_ws, size_t ws_size,
                              hipStream_t stream) {
  const float* x       = (const float*)d_in[0];
  const float* Wq      = (const float*)d_in[1];
  const float* Wk      = (const float*)d_in[2];
  const float* Wv      = (const float*)d_in[3];
  const float* conv_q  = (const float*)d_in[4];
  const float* conv_k  = (const float*)d_in[5];
  const float* conv_v  = (const float*)d_in[6];
  const float* Wb      = (const float*)d_in[7];
  const float* Wa      = (const float*)d_in[8];
  const float* A_log   = (const float*)d_in[9];
  const float* dt_bias = (const float*)d_in[10];
  const float* Wg      = (const float*)d_in[11];
  const float* norm_w  = (const float*)d_in[12];
  const float* Wo      = (const float*)d_in[13];
  float* out = (float*)d_out;
  float* ws  = (float*)d_ws;

  float* qpre  = ws + OF_QPRE;
  float* kpre  = ws + OF_KPRE;
  float* vpre  = ws + OF_VPRE;
  float* q     = ws + OF_Q;
  float* k     = ws + OF_K;
  float* v     = ws + OF_V;
  float* glog  = ws + OF_G;
  float* beta  = ws + OF_BETA;
  float* Kbar  = ws + OF_KBAR;
  float* BTm   = ws + OF_BT;
  float* CSb   = ws + OF_CS;
  float* o     = ws + OF_O;
  float* oo    = ws + OF_OO;
  float* gv    = ws + OF_GV;

  dim3 blk(256);

  // projections (bf16 MFMA)
  gemm_bf16<<<dim3(1024 / 128, BT_ROWS / 128), blk, 0, stream>>>(x, Wq, qpre, BT_ROWS, 1024, 1024);
  gemm_bf16<<<dim3(1024 / 128, BT_ROWS / 128), blk, 0, stream>>>(x, Wk, kpre, BT_ROWS, 1024, 1024);
  gemm_bf16<<<dim3(2048 / 128, BT_ROWS / 128), blk, 0, stream>>>(x, Wv, vpre, BT_ROWS, 2048, 1024);

  // beta + log-decay (fp32)
  beta_g_kernel<<<dim3(BT_ROWS * Hc / 4), blk, 0, stream>>>(x, Wb, Wa, A_log, dt_bias, beta, glog);

  // causal conv + silu
  conv_silu<<<dim3(1024 / 256, Tc / 32, Bc), blk, 0, stream>>>(qpre, conv_q, q, 1024);
  conv_silu<<<dim3(1024 / 256, Tc / 32, Bc), blk, 0, stream>>>(kpre, conv_k, k, 1024);
  conv_silu<<<dim3(2048 / 256, Tc / 32, Bc), blk, 0, stream>>>(vpre, conv_v, v, 2048);

  // l2norm q (scaled) and k
  l2norm_qk<<<dim3(BT_ROWS * Hc / 4), blk, 0, stream>>>(q, k);

  // chunked delta rule
  phase1<<<dim3(NCHUNK, Bc * Hc), blk, 0, stream>>>(q, k, v, glog, beta, Kbar, BTm, CSb);
  phase2<<<dim3(16, Bc * Hc), blk, 0, stream>>>(Kbar, BTm, CSb, q, k, v, o);

  // gv = x @ Wg (into v slot, dead after phase2)
  gemm_bf16<<<dim3(2048 / 128, BT_ROWS / 128), blk, 0, stream>>>(x, Wg, gv, BT_ROWS, 2048, 1024);

  // gated rmsnorm (oo over q+k, dead after phase2)
  gated_rmsnorm<<<dim3(BT_ROWS * Hc / 4), blk, 0, stream>>>(o, gv, norm_w, oo);

  // out = oo @ Wo
  gemm_bf16<<<dim3(1024 / 128, BT_ROWS / 128), blk, 0, stream>>>(oo, Wo, out, BT_ROWS, 1024, 2048);
}

// Round 7
// 601.196 us; speedup vs baseline: 3.4668x; 1.1890x over previous
//
#include <hip/hip_runtime.h>
#include <hip/hip_bf16.h>
#include <math.h>

// Problem dims (fixed by reference)
constexpr int Bc = 2, Tc = 1024, Dc = 1024, Hc = 8, DKc = 128, DVc = 256;
constexpr int BT_ROWS = Bc * Tc;                // 2048 rows
constexpr float QSCALE = 0.08838834764831845f;  // 128^-0.5
constexpr int NCHUNK = 16, CHUNK = 64;          // T = 16 chunks of 64

// ---------------- workspace layout (float offsets), extent = 16,809,984 f = 67.24MB (proven) ----
// 0..1M    xb (x as bf16, [2048][1024])           [cvt -> gv-gemm]
// 1..3M    Kbar [phase1 -> phase2] ; late: WgT(1..2M), WoT(2..3M)
// 3..4M    BTm  [phase1 -> phase2]
// 4..6M    qpre [gemm -> convq] ; then v(4..8M) ; late: oob(4..6M)
// 6..8M    kpre [gemm -> convk]
// 8..12M   vpre [gemm -> convv] ; then o [phase2 -> rmsnorm]
// 12..14M  q [convq -> phase2]  ; early: WqT(12..12.5) WkT(12.5..13) WvT(13..14, die pre-convq) ; late: gv(12..16M)
// 14..16M  k [convk -> phase2]
// 16M..    glog(16K), beta(16K)
constexpr size_t OF_XB   = 0;
constexpr size_t OF_KBAR = 1048576;
constexpr size_t OF_BTG  = 3145728;
constexpr size_t OF_QPRE = 4194304;
constexpr size_t OF_KPRE = 6291456;
constexpr size_t OF_VPRE = 8388608;
constexpr size_t OF_Q    = 12582912;
constexpr size_t OF_K    = 14680064;
constexpr size_t OF_V    = 4194304;   // over qpre+kpre (dead after convs)
constexpr size_t OF_G    = 16777216;
constexpr size_t OF_BETA = 16793600;
constexpr size_t OF_O    = 8388608;   // over vpre (dead after convv)
constexpr size_t OF_GV   = 12582912;  // over q+k (dead after phase2)
constexpr size_t OF_OOB  = 4194304;   // over v (dead after phase2), bf16 [2048][2048]
constexpr size_t OF_WQT  = 12582912;  // early, dead before convq writes q
constexpr size_t OF_WKT  = 13107200;
constexpr size_t OF_WVT  = 13631488;
constexpr size_t OF_WGT  = 1048576;   // late, over Kbar
constexpr size_t OF_WOT  = 2097152;   // late, over Kbar

using short8 = __attribute__((ext_vector_type(8))) short;
using short4v = __attribute__((ext_vector_type(4))) short;
using f32x4  = __attribute__((ext_vector_type(4))) float;

__device__ inline unsigned short f2bf(float f) {  // RNE fp32->bf16
  unsigned int u = __builtin_bit_cast(unsigned int, f);
  u += 0x7FFFu + ((u >> 16) & 1u);
  return (unsigned short)(u >> 16);
}

// async global->LDS 16B copy (dest wave-uniform base + lane*16; src per-lane)
__device__ inline void gload16(const void* g, void* l) {
  __builtin_amdgcn_global_load_lds(
      (const __attribute__((address_space(1))) unsigned int*)g,
      (__attribute__((address_space(3))) unsigned int*)l, 16, 0, 0);
}

// ---------------- fp32 -> bf16 elementwise (sizes divisible by 1024) ----------------
__global__ __launch_bounds__(256) void cvt_bf16(const float* __restrict__ X,
                                                unsigned short* __restrict__ Y) {
  int i = (blockIdx.x * 256 + threadIdx.x) * 4;
  float4 f = *(const float4*)&X[i];
  short4v o = {(short)f2bf(f.x), (short)f2bf(f.y), (short)f2bf(f.z), (short)f2bf(f.w)};
  *(short4v*)&Y[i] = o;
}

// ---------------- W[K][N] fp32 -> WT[N][K] bf16 (64x64 tiles) ----------------
__global__ __launch_bounds__(256) void transposeW(const float* __restrict__ W,
                                                  unsigned short* __restrict__ WT,
                                                  int K, int N) {
  __shared__ unsigned short Ls[64 * 66];
  const int n0 = blockIdx.x * 64, k0 = blockIdx.y * 64;
  const int t = threadIdx.x;
  {
    int r = t >> 2, c0 = (t & 3) * 16;
    const float* src = &W[(size_t)(k0 + r) * N + n0 + c0];
#pragma unroll
    for (int m = 0; m < 4; ++m) {
      float4 f = *(const float4*)&src[m * 4];
      unsigned short* p = &Ls[r * 66 + c0 + m * 4];
      p[0] = f2bf(f.x); p[1] = f2bf(f.y); p[2] = f2bf(f.z); p[3] = f2bf(f.w);
    }
  }
  __syncthreads();
  {
    int n = t >> 2, k4 = (t & 3) * 16;
    short8 o0, o1;
#pragma unroll
    for (int j = 0; j < 8; ++j) {
      o0[j] = (short)Ls[(k4 + j) * 66 + n];
      o1[j] = (short)Ls[(k4 + 8 + j) * 66 + n];
    }
    unsigned short* dst = &WT[(size_t)(n0 + n) * K + k0 + k4];
    *(short8*)dst = o0;
    *(short8*)(dst + 8) = o1;
  }
}

// ---------------- NT bf16-MFMA GEMM: C[M,N] f32 = A[M][K]bf16 @ BT[N][K]bf16 ----------------
// 128xTN tile, BK=64, 4 waves. Staging via global_load_lds(16B) with T2 source
// pre-swizzle (win ^= row&7) so ds_read_b128 fragment reads hit the 8-pass minimum.
template <int TN>
__global__ __launch_bounds__(256) void gemm_nt(const unsigned short* __restrict__ A,
                                               const unsigned short* __restrict__ BT,
                                               float* __restrict__ C,
                                               int M, int N, int K) {
  constexpr int NF = TN / 32;          // N-frags per wave (128->4, 64->2)
  __shared__ unsigned short As[128 * 64];
  __shared__ unsigned short Bs[TN * 64];
  const int tid = threadIdx.x, l = tid & 63, w = tid >> 6;
  const int m0 = blockIdx.y * 128, n0 = blockIdx.x * TN;
  const int wm = (w >> 1) * 64, wn = (w & 1) * (TN / 2);
  const int fr = l & 15, hk = l >> 4;
  const int srow = l >> 3, swin = l & 7;  // stage: 8 lanes/row, window id
  f32x4 acc[4][NF] = {};

  for (int k0 = 0; k0 < K; k0 += 64) {
    // ---- stage A (16KB, 16 chunks) ----
#pragma unroll
    for (int i = 0; i < 4; ++i) {
      int ch = i * 4 + w;
      int row = ch * 8 + srow;
      gload16((const char*)(A + (size_t)(m0 + row) * K + k0) + ((swin ^ (row & 7)) * 16),
              (char*)As + ch * 1024);
    }
    // ---- stage B (TN*128 bytes) ----
#pragma unroll
    for (int i = 0; i < TN / 32; ++i) {
      int ch = i * 4 + w;
      int row = ch * 8 + srow;
      gload16((const char*)(BT + (size_t)(n0 + row) * K + k0) + ((swin ^ (row & 7)) * 16),
              (char*)Bs + ch * 1024);
    }
    __syncthreads();
#pragma unroll
    for (int ks = 0; ks < 2; ++ks) {
      short8 a[4], b[NF];
#pragma unroll
      for (int mf = 0; mf < 4; ++mf) {
        int row = wm + mf * 16 + fr;
        a[mf] = *(const short8*)((const char*)As + row * 128 + (((hk + 4 * ks) ^ (row & 7)) * 16));
      }
#pragma unroll
      for (int nf = 0; nf < NF; ++nf) {
        int row = wn + nf * 16 + fr;
        b[nf] = *(const short8*)((const char*)Bs + row * 128 + (((hk + 4 * ks) ^ (row & 7)) * 16));
      }
#pragma unroll
      for (int mf = 0; mf < 4; ++mf)
#pragma unroll
        for (int nf = 0; nf < NF; ++nf)
          acc[mf][nf] = __builtin_amdgcn_mfma_f32_16x16x32_bf16(a[mf], b[nf], acc[mf][nf], 0, 0, 0);
    }
    __syncthreads();
  }
  const int orow = (l >> 4) * 4;
#pragma unroll
  for (int mf = 0; mf < 4; ++mf)
#pragma unroll
    for (int nf = 0; nf < NF; ++nf)
#pragma unroll
      for (int r = 0; r < 4; ++r)
        C[(size_t)(m0 + wm + mf * 16 + orow + r) * N + n0 + wn + nf * 16 + fr] = acc[mf][nf][r];
}

// ---------------- depthwise causal conv1d (K=4) + silu ----------------
__global__ __launch_bounds__(256) void conv_silu(const float* __restrict__ X,
                                                 const float* __restrict__ W,
                                                 float* __restrict__ Y, int C) {
  int c = blockIdx.x * 256 + threadIdx.x;
  if (c >= C) return;
  int b  = blockIdx.z;
  int t0 = blockIdx.y * 32;
  float4 w = *(const float4*)&W[c * 4];
  const float* xp = X + (size_t)b * Tc * C + c;
  float* yp = Y + (size_t)b * Tc * C + c;
  float x0 = (t0 >= 3) ? xp[(size_t)(t0 - 3) * C] : 0.f;
  float x1 = (t0 >= 2) ? xp[(size_t)(t0 - 2) * C] : 0.f;
  float x2 = (t0 >= 1) ? xp[(size_t)(t0 - 1) * C] : 0.f;
  for (int t = t0; t < t0 + 32; ++t) {
    float x3 = xp[(size_t)t * C];
    float a  = w.x * x0 + w.y * x1 + w.z * x2 + w.w * x3;
    float y  = a / (1.f + __expf(-a));
    yp[(size_t)t * C] = y;
    x0 = x1; x1 = x2; x2 = x3;
  }
}

// ---------------- beta + g_log: one wave per (b,t,h) ----------------
__global__ __launch_bounds__(256) void beta_g_kernel(const float* __restrict__ X,
                                                     const float* __restrict__ Wb,
                                                     const float* __restrict__ Wa,
                                                     const float* __restrict__ A_log,
                                                     const float* __restrict__ dt_bias,
                                                     float* __restrict__ beta,
                                                     float* __restrict__ glog) {
  int w    = blockIdx.x * 4 + (threadIdx.x >> 6);
  int lane = threadIdx.x & 63;
  int h  = w & 7;
  int bt = w >> 3;
  const float* x = X + (size_t)bt * Dc;
  float sb = 0.f, sa = 0.f;
#pragma unroll
  for (int i = 0; i < 16; ++i) {
    int d = lane + 64 * i;
    float xv = x[d];
    sb = fmaf(xv, Wb[d * 8 + h], sb);
    sa = fmaf(xv, Wa[d * 8 + h], sa);
  }
#pragma unroll
  for (int m = 1; m < 64; m <<= 1) {
    sb += __shfl_xor(sb, m);
    sa += __shfl_xor(sa, m);
  }
  if (lane == 0) {
    beta[w] = 1.f / (1.f + expf(-sb));
    float z  = sa + dt_bias[h];
    float sp = (z > 20.f) ? z : log1pf(expf(z));
    glog[w]  = -expf(A_log[h]) * sp;
  }
}

// ---------------- l2norm q (scaled) and k: one wave per (b,t,h) ----------------
__global__ __launch_bounds__(256) void l2norm_qk(float* __restrict__ Q, float* __restrict__ K) {
  int w    = blockIdx.x * 4 + (threadIdx.x >> 6);
  int lane = threadIdx.x & 63;
  int h = w & 7;
  size_t bt = (size_t)(w >> 3);
  float* qp = Q + bt * (Hc * DKc) + h * DKc + lane * 2;
  float* kp = K + bt * (Hc * DKc) + h * DKc + lane * 2;
  float2 q2 = *(float2*)qp;
  float2 k2 = *(float2*)kp;
  float sq = q2.x * q2.x + q2.y * q2.y;
  float sk = k2.x * k2.x + k2.y * k2.y;
#pragma unroll
  for (int m = 1; m < 64; m <<= 1) {
    sq += __shfl_xor(sq, m);
    sk += __shfl_xor(sk, m);
  }
  float rq = rsqrtf(sq + 1e-6f) * QSCALE;
  float rk = rsqrtf(sk + 1e-6f);
  q2.x *= rq; q2.y *= rq;
  k2.x *= rk; k2.y *= rk;
  *(float2*)qp = q2;
  *(float2*)kp = k2;
}

// ---------------- Phase 1: per (bh, chunk) precompute (no CS output) ----------------
__global__ __launch_bounds__(256) void phase1(const float* __restrict__ Q,
                                              const float* __restrict__ K,
                                              float* __restrict__ V,
                                              const float* __restrict__ G,
                                              const float* __restrict__ BETA,
                                              float* __restrict__ Kbar,
                                              float* __restrict__ BTm) {
  constexpr int SK = 68;
  __shared__ float sm[25984];
  float* kcT  = sm;            // [128][68]
  float* qcT  = sm + 8704;     // [128][68]
  float* vld  = sm;            // [64][256] (reuse after barrier)
  float* Amat = sm + 17408;    // [64][65]
  float* Mmat = sm + 21568;    // [64][65]
  float* cs   = sm + 25728;
  float* bet  = sm + 25856;
  float* wk   = sm + 25920;
  const int tid = threadIdx.x;
  const int c = blockIdx.x, bh = blockIdx.y;
  const int b = bh >> 3, h = bh & 7;
  const int t0 = c * CHUNK;
  const size_t cb = (size_t)bh * NCHUNK + c;

  if (tid < 64) {
    cs[tid]  = G[((size_t)(b * Tc + t0 + tid)) * 8 + h];
    bet[tid] = BETA[((size_t)(b * Tc + t0 + tid)) * 8 + h];
  }
  {
    int r = tid >> 2, dq = (tid & 3) * 32;
    const float4* kg = (const float4*)&K[((size_t)(b * Tc + t0 + r)) * 1024 + h * 128 + dq];
    const float4* qg = (const float4*)&Q[((size_t)(b * Tc + t0 + r)) * 1024 + h * 128 + dq];
#pragma unroll
    for (int m = 0; m < 8; ++m) {
      float4 kv = kg[m], qv = qg[m];
      int d = dq + m * 4;
      kcT[(d + 0) * SK + r] = kv.x; kcT[(d + 1) * SK + r] = kv.y;
      kcT[(d + 2) * SK + r] = kv.z; kcT[(d + 3) * SK + r] = kv.w;
      qcT[(d + 0) * SK + r] = qv.x; qcT[(d + 1) * SK + r] = qv.y;
      qcT[(d + 2) * SK + r] = qv.z; qcT[(d + 3) * SK + r] = qv.w;
    }
  }
  __syncthreads();
  if (tid == 0) {
    float a = 0.f;
    for (int i = 0; i < 64; ++i) { a += cs[i]; cs[i] = a; }
  }
  __syncthreads();
  if (tid < 64) {
    float gv_ = __expf(cs[tid]);
    wk[tid]  = bet[tid] * gv_;
  }
  for (int e = tid; e < 4096; e += 256) {
    int i = e >> 6, s = e & 63;
    float av = 0.f;
    if (s < i) {
      float acc = 0.f;
      for (int d = 0; d < 128; ++d) acc += kcT[d * SK + i] * kcT[d * SK + s];
      av = bet[i] * __expf(cs[i] - cs[s]) * acc;
    }
    Amat[i * 65 + s] = av;
  }
  for (int e = tid; e < 4096; e += 256) {
    int s = e >> 6, i = e & 63;
    float outv = 0.f;
    if (s <= i) {
      float acc = 0.f;
      for (int d = 0; d < 128; ++d) acc += qcT[d * SK + i] * kcT[d * SK + s];
      outv = __expf(cs[i] - cs[s]) * acc;
    }
    BTm[cb * 4096 + (size_t)s * 64 + i] = outv;
  }
  __syncthreads();
  if (tid < 64) {
    int j = tid;
    for (int i = 0; i < 64; ++i) {
      float m = (i == j) ? 1.f : 0.f;
      for (int s = 0; s < i; ++s) m -= Amat[i * 65 + s] * Mmat[s * 65 + j];
      Mmat[i * 65 + j] = m;
    }
  }
  __syncthreads();
  for (int e = tid; e < 2048; e += 256) {
    int i = e & 63, d0 = ((e >> 6) & 31) * 4;
    float a0 = 0, a1 = 0, a2 = 0, a3 = 0;
#pragma unroll 4
    for (int s = 0; s < 64; ++s) {
      float m_ = Mmat[i * 65 + s] * wk[s];
      a0 = fmaf(m_, kcT[(d0 + 0) * SK + s], a0);
      a1 = fmaf(m_, kcT[(d0 + 1) * SK + s], a1);
      a2 = fmaf(m_, kcT[(d0 + 2) * SK + s], a2);
      a3 = fmaf(m_, kcT[(d0 + 3) * SK + s], a3);
    }
    float4 w4 = {a0, a1, a2, a3};
    *(float4*)&Kbar[cb * 8192 + (size_t)i * 128 + d0] = w4;
  }
  __syncthreads();
  {
    int r = tid >> 2, j0 = (tid & 3) * 64;
    const float4* vg = (const float4*)&V[((size_t)(b * Tc + t0 + r)) * 2048 + h * 256 + j0];
#pragma unroll
    for (int m = 0; m < 16; ++m) *(float4*)&vld[r * 256 + j0 + m * 4] = vg[m];
  }
  __syncthreads();
  for (int e = tid; e < 4096; e += 256) {
    int i = e >> 6, j0 = (e & 63) * 4;
    float a0 = 0, a1 = 0, a2 = 0, a3 = 0;
    for (int s = 0; s < 64; ++s) {
      float m_ = Mmat[i * 65 + s] * bet[s];
      float4 vv = *(const float4*)&vld[s * 256 + j0];
      a0 = fmaf(m_, vv.x, a0); a1 = fmaf(m_, vv.y, a1);
      a2 = fmaf(m_, vv.z, a2); a3 = fmaf(m_, vv.w, a3);
    }
    float4 o4 = {a0, a1, a2, a3};
    *(float4*)&V[((size_t)(b * Tc + t0 + i)) * 2048 + h * 256 + j0] = o4;
  }
}

// ---------------- Phase 2: serial-over-chunks, column-parallel (R6-proven) ----------------
// csL recomputed from glog via wave shfl-scan (CS buffer eliminated).
__global__ __launch_bounds__(256) void phase2(const float* __restrict__ KbarG,
                                              const float* __restrict__ BTmG,
                                              const float* __restrict__ GL,
                                              const float* __restrict__ Qp,
                                              const float* __restrict__ Kp,
                                              const float* __restrict__ VBAR,
                                              float* __restrict__ O) {
  __shared__ float S[16 * 132];
  __shared__ float KbL[64 * 128];
  __shared__ float qcL[64 * 128];
  __shared__ float K2L[64 * 128];
  __shared__ float BcL[64 * 64];
  __shared__ float uL[64 * 20];
  __shared__ float csL[64], rsL[64], gamL[64];
  const int tid = threadIdx.x;
  const int l = tid & 63, w = tid >> 6;
  const int jb = blockIdx.x, bh = blockIdx.y;
  const int b = bh >> 3, h = bh & 7;
  const int i = l;
  const int j0 = w * 4;
  const int swzi = (i & 7) << 2;
  const int d0u = (tid & 31) * 4;
  const int jq = tid >> 5;
  const size_t colbase = (size_t)h * 256 + jb * 16;

  for (int e = tid; e < 16 * 132; e += 256) S[e] = 0.f;

  for (int c = 0; c < NCHUNK; ++c) {
    const size_t cb = (size_t)bh * NCHUNK + c;
    const int bT0 = b * Tc + c * CHUNK;
    __syncthreads();
    // cumsum of glog over the chunk (wave-0 inclusive scan)
    if (tid < 64) {
      float gi = GL[((size_t)(bT0 + tid)) * 8 + h];
#pragma unroll
      for (int off = 1; off < 64; off <<= 1) {
        float p = __shfl_up(gi, off);
        if (tid >= off) gi += p;
      }
      csL[tid] = gi;
    }
    {
      const char* kbg = (const char*)(KbarG + cb * 8192);
#pragma unroll
      for (int ic = 0; ic < 8; ++ic) {
        int ch = ic * 4 + w;
        int row = 2 * ch + (l >> 5);
        int inrow = (l & 31) * 16;
        int swz = inrow ^ ((row & 7) << 4);
        gload16(kbg + row * 512 + swz, (char*)KbL + ch * 1024);
        gload16((const char*)(Qp + ((size_t)(bT0 + row)) * 1024 + h * 128) + swz,
                (char*)qcL + ch * 1024);
        gload16((const char*)(Kp + ((size_t)(bT0 + row)) * 1024 + h * 128) + inrow,
                (char*)K2L + ch * 1024);
      }
      const char* btg = (const char*)(BTmG + cb * 4096);
#pragma unroll
      for (int ic = 0; ic < 4; ++ic) {
        int ch = ic * 4 + w;
        gload16(btg + ch * 1024 + l * 16, (char*)BcL + ch * 1024);
      }
    }
    __syncthreads();
    if (tid < 64) {
      gamL[tid] = __expf(csL[tid]);
      rsL[tid]  = __expf(csL[63] - csL[tid]);
    }
    float ua[4] = {}, ra[4] = {};
#pragma unroll 4
    for (int d = 0; d < 128; d += 4) {
      int ds = d ^ swzi;
      float4 kb = *(const float4*)&KbL[i * 128 + ds];
      float4 qg = *(const float4*)&qcL[i * 128 + ds];
#pragma unroll
      for (int jj = 0; jj < 4; ++jj) {
        float4 s4 = *(const float4*)&S[(j0 + jj) * 132 + d];
        ua[jj] = fmaf(kb.x, s4.x, fmaf(kb.y, s4.y, fmaf(kb.z, s4.z, fmaf(kb.w, s4.w, ua[jj]))));
        ra[jj] = fmaf(qg.x, s4.x, fmaf(qg.y, s4.y, fmaf(qg.z, s4.z, fmaf(qg.w, s4.w, ra[jj]))));
      }
    }
    float4 vb = *(const float4*)&VBAR[((size_t)(bT0 + i)) * 2048 + colbase + j0];
    float4 uf = {vb.x - ua[0], vb.y - ua[1], vb.z - ua[2], vb.w - ua[3]};
    *(float4*)&uL[i * 20 + j0] = uf;
    __syncthreads();
    float ba[4] = {};
#pragma unroll 4
    for (int s = 0; s < 64; ++s) {
      float bv = BcL[s * 64 + i];
      float4 u4 = *(const float4*)&uL[s * 20 + j0];
      ba[0] = fmaf(bv, u4.x, ba[0]); ba[1] = fmaf(bv, u4.y, ba[1]);
      ba[2] = fmaf(bv, u4.z, ba[2]); ba[3] = fmaf(bv, u4.w, ba[3]);
    }
    float gi = gamL[i];
    float4 o4 = {gi * ra[0] + ba[0], gi * ra[1] + ba[1],
                 gi * ra[2] + ba[2], gi * ra[3] + ba[3]};
    *(float4*)&O[((size_t)(bT0 + i)) * 2048 + colbase + j0] = o4;
    float sa[2][4] = {};
#pragma unroll 4
    for (int s = 0; s < 64; ++s) {
      float4 k2 = *(const float4*)&K2L[s * 128 + d0u];
      float rv = rsL[s];
      float u0 = uL[s * 20 + 2 * jq] * rv;
      float u1 = uL[s * 20 + 2 * jq + 1] * rv;
      sa[0][0] = fmaf(k2.x, u0, sa[0][0]); sa[0][1] = fmaf(k2.y, u0, sa[0][1]);
      sa[0][2] = fmaf(k2.z, u0, sa[0][2]); sa[0][3] = fmaf(k2.w, u0, sa[0][3]);
      sa[1][0] = fmaf(k2.x, u1, sa[1][0]); sa[1][1] = fmaf(k2.y, u1, sa[1][1]);
      sa[1][2] = fmaf(k2.z, u1, sa[1][2]); sa[1][3] = fmaf(k2.w, u1, sa[1][3]);
    }
    float gC = gamL[63];
#pragma unroll
    for (int jj = 0; jj < 2; ++jj) {
      float4 sv = *(const float4*)&S[(2 * jq + jj) * 132 + d0u];
      sv.x = fmaf(gC, sv.x, sa[jj][0]); sv.y = fmaf(gC, sv.y, sa[jj][1]);
      sv.z = fmaf(gC, sv.z, sa[jj][2]); sv.w = fmaf(gC, sv.w, sa[jj][3]);
      *(float4*)&S[(2 * jq + jj) * 132 + d0u] = sv;
    }
  }
}

// ---------------- fused gated RMSNorm -> bf16 output ----------------
__global__ __launch_bounds__(256) void gated_rmsnorm(const float* __restrict__ O,
                                                     const float* __restrict__ GV,
                                                     const float* __restrict__ NW,
                                                     unsigned short* __restrict__ OO) {
  int w    = blockIdx.x * 4 + (threadIdx.x >> 6);
  int lane = threadIdx.x & 63;
  size_t base = (size_t)w * DVc;
  float4 o4 = *(const float4*)&O[base + lane * 4];
  float ss = o4.x * o4.x + o4.y * o4.y + o4.z * o4.z + o4.w * o4.w;
#pragma unroll
  for (int m = 1; m < 64; m <<= 1) ss += __shfl_xor(ss, m);
  float r = rsqrtf(ss * (1.f / 256.f) + 1e-5f);
  float4 g4 = *(const float4*)&GV[base + lane * 4];
  float4 w4 = *(const float4*)&NW[lane * 4];
  float4 out;
  out.x = o4.x * r * w4.x * (g4.x / (1.f + __expf(-g4.x)));
  out.y = o4.y * r * w4.y * (g4.y / (1.f + __expf(-g4.y)));
  out.z = o4.z * r * w4.z * (g4.z / (1.f + __expf(-g4.z)));
  out.w = o4.w * r * w4.w * (g4.w / (1.f + __expf(-g4.w)));
  short4v ob = {(short)f2bf(out.x), (short)f2bf(out.y), (short)f2bf(out.z), (short)f2bf(out.w)};
  *(short4v*)&OO[base + lane * 4] = ob;
}

// ---------------- launcher ----------------
extern "C" void kernel_launch(void* const* d_in, const int* in_sizes, int n_in,
                              void* d_out, int out_size, void* d_ws, size_t ws_size,
                              hipStream_t stream) {
  const float* x       = (const float*)d_in[0];
  const float* Wq      = (const float*)d_in[1];
  const float* Wk      = (const float*)d_in[2];
  const float* Wv      = (const float*)d_in[3];
  const float* conv_q  = (const float*)d_in[4];
  const float* conv_k  = (const float*)d_in[5];
  const float* conv_v  = (const float*)d_in[6];
  const float* Wb      = (const float*)d_in[7];
  const float* Wa      = (const float*)d_in[8];
  const float* A_log   = (const float*)d_in[9];
  const float* dt_bias = (const float*)d_in[10];
  const float* Wg      = (const float*)d_in[11];
  const float* norm_w  = (const float*)d_in[12];
  const float* Wo      = (const float*)d_in[13];
  float* out = (float*)d_out;
  float* ws  = (float*)d_ws;

  unsigned short* xb  = (unsigned short*)(ws + OF_XB);
  unsigned short* WqT = (unsigned short*)(ws + OF_WQT);
  unsigned short* WkT = (unsigned short*)(ws + OF_WKT);
  unsigned short* WvT = (unsigned short*)(ws + OF_WVT);
  unsigned short* WgT = (unsigned short*)(ws + OF_WGT);
  unsigned short* WoT = (unsigned short*)(ws + OF_WOT);
  unsigned short* oob = (unsigned short*)(ws + OF_OOB);
  float* qpre  = ws + OF_QPRE;
  float* kpre  = ws + OF_KPRE;
  float* vpre  = ws + OF_VPRE;
  float* q     = ws + OF_Q;
  float* k     = ws + OF_K;
  float* v     = ws + OF_V;
  float* glog  = ws + OF_G;
  float* beta  = ws + OF_BETA;
  float* Kbar  = ws + OF_KBAR;
  float* BTm   = ws + OF_BTG;
  float* o     = ws + OF_O;
  float* gv    = ws + OF_GV;

  dim3 blk(256);

  // bf16 conversions (early)
  cvt_bf16<<<dim3(2048), blk, 0, stream>>>(x, xb);                       // 2M elems
  transposeW<<<dim3(16, 16), blk, 0, stream>>>(Wq, WqT, 1024, 1024);
  transposeW<<<dim3(16, 16), blk, 0, stream>>>(Wk, WkT, 1024, 1024);
  transposeW<<<dim3(32, 16), blk, 0, stream>>>(Wv, WvT, 1024, 2048);

  // projections (MFMA NT)
  gemm_nt<64><<<dim3(16, 16), blk, 0, stream>>>(xb, WqT, qpre, BT_ROWS, 1024, 1024);
  gemm_nt<64><<<dim3(16, 16), blk, 0, stream>>>(xb, WkT, kpre, BT_ROWS, 1024, 1024);
  gemm_nt<128><<<dim3(16, 16), blk, 0, stream>>>(xb, WvT, vpre, BT_ROWS, 2048, 1024);

  // beta + log-decay
  beta_g_kernel<<<dim3(BT_ROWS * Hc / 4), blk, 0, stream>>>(x, Wb, Wa, A_log, dt_bias, beta, glog);

  // causal conv + silu
  conv_silu<<<dim3(1024 / 256, Tc / 32, Bc), blk, 0, stream>>>(qpre, conv_q, q, 1024);
  conv_silu<<<dim3(1024 / 256, Tc / 32, Bc), blk, 0, stream>>>(kpre, conv_k, k, 1024);
  conv_silu<<<dim3(2048 / 256, Tc / 32, Bc), blk, 0, stream>>>(vpre, conv_v, v, 2048);

  // l2norm q (scaled) and k
  l2norm_qk<<<dim3(BT_ROWS * Hc / 4), blk, 0, stream>>>(q, k);

  // chunked delta rule
  phase1<<<dim3(NCHUNK, Bc * Hc), blk, 0, stream>>>(q, k, v, glog, beta, Kbar, BTm);
  phase2<<<dim3(16, Bc * Hc), blk, 0, stream>>>(Kbar, BTm, glog, q, k, v, o);

  // gv = x @ Wg (late: WgT over dead Kbar region)
  transposeW<<<dim3(32, 16), blk, 0, stream>>>(Wg, WgT, 1024, 2048);
  gemm_nt<128><<<dim3(16, 16), blk, 0, stream>>>(xb, WgT, gv, BT_ROWS, 2048, 1024);

  // gated rmsnorm -> bf16 oob
  transposeW<<<dim3(16, 32), blk, 0, stream>>>(Wo, WoT, 2048, 1024);
  gated_rmsnorm<<<dim3(BT_ROWS * Hc / 4), blk, 0, stream>>>(o, gv, norm_w, oob);

  // out = oob @ WoT
  gemm_nt<64><<<dim3(16, 16), blk, 0, stream>>>(oob, WoT, out, BT_ROWS, 1024, 2048);
}

// Round 8
// 597.757 us; speedup vs baseline: 3.4867x; 1.0058x over previous
//
#include <hip/hip_runtime.h>
#include <hip/hip_bf16.h>
#include <math.h>

// Problem dims (fixed by reference)
constexpr int Bc = 2, Tc = 1024, Dc = 1024, Hc = 8, DKc = 128, DVc = 256;
constexpr int BT_ROWS = Bc * Tc;                // 2048 rows
constexpr float QSCALE = 0.08838834764831845f;  // 128^-0.5
constexpr int NCHUNK = 16, CHUNK = 64;          // T = 16 chunks of 64

// ---------------- workspace layout (float offsets), extent = 16,809,984 f (proven) ----
constexpr size_t OF_XB   = 0;
constexpr size_t OF_KBAR = 1048576;
constexpr size_t OF_BTG  = 3145728;
constexpr size_t OF_QPRE = 4194304;
constexpr size_t OF_KPRE = 6291456;
constexpr size_t OF_VPRE = 8388608;
constexpr size_t OF_Q    = 12582912;
constexpr size_t OF_K    = 14680064;
constexpr size_t OF_V    = 4194304;   // over qpre+kpre (dead after convs)
constexpr size_t OF_G    = 16777216;
constexpr size_t OF_BETA = 16793600;
constexpr size_t OF_O    = 8388608;   // over vpre (dead after convv)
constexpr size_t OF_GV   = 12582912;  // over q+k (dead after phase2)
constexpr size_t OF_OOB  = 4194304;   // over v (dead after phase2), bf16 [2048][2048]
constexpr size_t OF_WQT  = 12582912;  // early, dead before convq writes q
constexpr size_t OF_WKT  = 13107200;
constexpr size_t OF_WVT  = 13631488;
constexpr size_t OF_WGT  = 1048576;   // late, over Kbar
constexpr size_t OF_WOT  = 2097152;   // late, over Kbar

using short8 = __attribute__((ext_vector_type(8))) short;
using short4v = __attribute__((ext_vector_type(4))) short;
using f32x4  = __attribute__((ext_vector_type(4))) float;

__device__ inline unsigned short f2bf(float f) {  // RNE fp32->bf16
  unsigned int u = __builtin_bit_cast(unsigned int, f);
  u += 0x7FFFu + ((u >> 16) & 1u);
  return (unsigned short)(u >> 16);
}

// async global->LDS 16B copy (dest wave-uniform base + lane*16; src per-lane)
__device__ inline void gload16(const void* g, void* l) {
  __builtin_amdgcn_global_load_lds(
      (const __attribute__((address_space(1))) unsigned int*)g,
      (__attribute__((address_space(3))) unsigned int*)l, 16, 0, 0);
}

// ---------------- fp32 -> bf16 elementwise (sizes divisible by 1024) ----------------
__global__ __launch_bounds__(256) void cvt_bf16(const float* __restrict__ X,
                                                unsigned short* __restrict__ Y) {
  int i = (blockIdx.x * 256 + threadIdx.x) * 4;
  float4 f = *(const float4*)&X[i];
  short4v o = {(short)f2bf(f.x), (short)f2bf(f.y), (short)f2bf(f.z), (short)f2bf(f.w)};
  *(short4v*)&Y[i] = o;
}

// ---------------- W[K][N] fp32 -> WT[N][K] bf16 (64x64 tiles) ----------------
__global__ __launch_bounds__(256) void transposeW(const float* __restrict__ W,
                                                  unsigned short* __restrict__ WT,
                                                  int K, int N) {
  __shared__ unsigned short Ls[64 * 66];
  const int n0 = blockIdx.x * 64, k0 = blockIdx.y * 64;
  const int t = threadIdx.x;
  {
    int r = t >> 2, c0 = (t & 3) * 16;
    const float* src = &W[(size_t)(k0 + r) * N + n0 + c0];
#pragma unroll
    for (int m = 0; m < 4; ++m) {
      float4 f = *(const float4*)&src[m * 4];
      unsigned short* p = &Ls[r * 66 + c0 + m * 4];
      p[0] = f2bf(f.x); p[1] = f2bf(f.y); p[2] = f2bf(f.z); p[3] = f2bf(f.w);
    }
  }
  __syncthreads();
  {
    int n = t >> 2, k4 = (t & 3) * 16;
    short8 o0, o1;
#pragma unroll
    for (int j = 0; j < 8; ++j) {
      o0[j] = (short)Ls[(k4 + j) * 66 + n];
      o1[j] = (short)Ls[(k4 + 8 + j) * 66 + n];
    }
    unsigned short* dst = &WT[(size_t)(n0 + n) * K + k0 + k4];
    *(short8*)dst = o0;
    *(short8*)(dst + 8) = o1;
  }
}

// ---------------- NT bf16-MFMA GEMM: C[M,N] f32 = A[M][K]bf16 @ BT[N][K]bf16 ----------------
template <int TN>
__global__ __launch_bounds__(256) void gemm_nt(const unsigned short* __restrict__ A,
                                               const unsigned short* __restrict__ BT,
                                               float* __restrict__ C,
                                               int M, int N, int K) {
  constexpr int NF = TN / 32;
  __shared__ unsigned short As[128 * 64];
  __shared__ unsigned short Bs[TN * 64];
  const int tid = threadIdx.x, l = tid & 63, w = tid >> 6;
  const int m0 = blockIdx.y * 128, n0 = blockIdx.x * TN;
  const int wm = (w >> 1) * 64, wn = (w & 1) * (TN / 2);
  const int fr = l & 15, hk = l >> 4;
  const int srow = l >> 3, swin = l & 7;
  f32x4 acc[4][NF] = {};

  for (int k0 = 0; k0 < K; k0 += 64) {
#pragma unroll
    for (int i = 0; i < 4; ++i) {
      int ch = i * 4 + w;
      int row = ch * 8 + srow;
      gload16((const char*)(A + (size_t)(m0 + row) * K + k0) + ((swin ^ (row & 7)) * 16),
              (char*)As + ch * 1024);
    }
#pragma unroll
    for (int i = 0; i < TN / 32; ++i) {
      int ch = i * 4 + w;
      int row = ch * 8 + srow;
      gload16((const char*)(BT + (size_t)(n0 + row) * K + k0) + ((swin ^ (row & 7)) * 16),
              (char*)Bs + ch * 1024);
    }
    __syncthreads();
#pragma unroll
    for (int ks = 0; ks < 2; ++ks) {
      short8 a[4], b[NF];
#pragma unroll
      for (int mf = 0; mf < 4; ++mf) {
        int row = wm + mf * 16 + fr;
        a[mf] = *(const short8*)((const char*)As + row * 128 + (((hk + 4 * ks) ^ (row & 7)) * 16));
      }
#pragma unroll
      for (int nf = 0; nf < NF; ++nf) {
        int row = wn + nf * 16 + fr;
        b[nf] = *(const short8*)((const char*)Bs + row * 128 + (((hk + 4 * ks) ^ (row & 7)) * 16));
      }
#pragma unroll
      for (int mf = 0; mf < 4; ++mf)
#pragma unroll
        for (int nf = 0; nf < NF; ++nf)
          acc[mf][nf] = __builtin_amdgcn_mfma_f32_16x16x32_bf16(a[mf], b[nf], acc[mf][nf], 0, 0, 0);
    }
    __syncthreads();
  }
  const int orow = (l >> 4) * 4;
#pragma unroll
  for (int mf = 0; mf < 4; ++mf)
#pragma unroll
    for (int nf = 0; nf < NF; ++nf)
#pragma unroll
      for (int r = 0; r < 4; ++r)
        C[(size_t)(m0 + wm + mf * 16 + orow + r) * N + n0 + wn + nf * 16 + fr] = acc[mf][nf][r];
}

// ---------------- depthwise causal conv1d (K=4) + silu ----------------
__global__ __launch_bounds__(256) void conv_silu(const float* __restrict__ X,
                                                 const float* __restrict__ W,
                                                 float* __restrict__ Y, int C) {
  int c = blockIdx.x * 256 + threadIdx.x;
  if (c >= C) return;
  int b  = blockIdx.z;
  int t0 = blockIdx.y * 32;
  float4 w = *(const float4*)&W[c * 4];
  const float* xp = X + (size_t)b * Tc * C + c;
  float* yp = Y + (size_t)b * Tc * C + c;
  float x0 = (t0 >= 3) ? xp[(size_t)(t0 - 3) * C] : 0.f;
  float x1 = (t0 >= 2) ? xp[(size_t)(t0 - 2) * C] : 0.f;
  float x2 = (t0 >= 1) ? xp[(size_t)(t0 - 1) * C] : 0.f;
  for (int t = t0; t < t0 + 32; ++t) {
    float x3 = xp[(size_t)t * C];
    float a  = w.x * x0 + w.y * x1 + w.z * x2 + w.w * x3;
    float y  = a / (1.f + __expf(-a));
    yp[(size_t)t * C] = y;
    x0 = x1; x1 = x2; x2 = x3;
  }
}

// ---------------- beta + g_log: one wave per (b,t,h) ----------------
__global__ __launch_bounds__(256) void beta_g_kernel(const float* __restrict__ X,
                                                     const float* __restrict__ Wb,
                                                     const float* __restrict__ Wa,
                                                     const float* __restrict__ A_log,
                                                     const float* __restrict__ dt_bias,
                                                     float* __restrict__ beta,
                                                     float* __restrict__ glog) {
  int w    = blockIdx.x * 4 + (threadIdx.x >> 6);
  int lane = threadIdx.x & 63;
  int h  = w & 7;
  int bt = w >> 3;
  const float* x = X + (size_t)bt * Dc;
  float sb = 0.f, sa = 0.f;
#pragma unroll
  for (int i = 0; i < 16; ++i) {
    int d = lane + 64 * i;
    float xv = x[d];
    sb = fmaf(xv, Wb[d * 8 + h], sb);
    sa = fmaf(xv, Wa[d * 8 + h], sa);
  }
#pragma unroll
  for (int m = 1; m < 64; m <<= 1) {
    sb += __shfl_xor(sb, m);
    sa += __shfl_xor(sa, m);
  }
  if (lane == 0) {
    beta[w] = 1.f / (1.f + expf(-sb));
    float z  = sa + dt_bias[h];
    float sp = (z > 20.f) ? z : log1pf(expf(z));
    glog[w]  = -expf(A_log[h]) * sp;
  }
}

// ---------------- l2norm q (scaled) and k: one wave per (b,t,h) ----------------
__global__ __launch_bounds__(256) void l2norm_qk(float* __restrict__ Q, float* __restrict__ K) {
  int w    = blockIdx.x * 4 + (threadIdx.x >> 6);
  int lane = threadIdx.x & 63;
  int h = w & 7;
  size_t bt = (size_t)(w >> 3);
  float* qp = Q + bt * (Hc * DKc) + h * DKc + lane * 2;
  float* kp = K + bt * (Hc * DKc) + h * DKc + lane * 2;
  float2 q2 = *(float2*)qp;
  float2 k2 = *(float2*)kp;
  float sq = q2.x * q2.x + q2.y * q2.y;
  float sk = k2.x * k2.x + k2.y * k2.y;
#pragma unroll
  for (int m = 1; m < 64; m <<= 1) {
    sq += __shfl_xor(sq, m);
    sk += __shfl_xor(sk, m);
  }
  float rq = rsqrtf(sq + 1e-6f) * QSCALE;
  float rk = rsqrtf(sk + 1e-6f);
  q2.x *= rq; q2.y *= rq;
  k2.x *= rk; k2.y *= rk;
  *(float2*)qp = q2;
  *(float2*)kp = k2;
}

// ---------------- Phase 1: per (bh, chunk) precompute ----------------
__global__ __launch_bounds__(256) void phase1(const float* __restrict__ Q,
                                              const float* __restrict__ K,
                                              float* __restrict__ V,
                                              const float* __restrict__ G,
                                              const float* __restrict__ BETA,
                                              float* __restrict__ Kbar,
                                              float* __restrict__ BTm) {
  constexpr int SK = 68;
  __shared__ float sm[25984];
  float* kcT  = sm;            // [128][68]
  float* qcT  = sm + 8704;     // [128][68]
  float* vld  = sm;            // [64][256] (reuse after barrier)
  float* Amat = sm + 17408;    // [64][65]
  float* Mmat = sm + 21568;    // [64][65]
  float* cs   = sm + 25728;
  float* bet  = sm + 25856;
  float* wk   = sm + 25920;
  const int tid = threadIdx.x;
  const int c = blockIdx.x, bh = blockIdx.y;
  const int b = bh >> 3, h = bh & 7;
  const int t0 = c * CHUNK;
  const size_t cb = (size_t)bh * NCHUNK + c;

  if (tid < 64) {
    cs[tid]  = G[((size_t)(b * Tc + t0 + tid)) * 8 + h];
    bet[tid] = BETA[((size_t)(b * Tc + t0 + tid)) * 8 + h];
  }
  {
    int r = tid >> 2, dq = (tid & 3) * 32;
    const float4* kg = (const float4*)&K[((size_t)(b * Tc + t0 + r)) * 1024 + h * 128 + dq];
    const float4* qg = (const float4*)&Q[((size_t)(b * Tc + t0 + r)) * 1024 + h * 128 + dq];
#pragma unroll
    for (int m = 0; m < 8; ++m) {
      float4 kv = kg[m], qv = qg[m];
      int d = dq + m * 4;
      kcT[(d + 0) * SK + r] = kv.x; kcT[(d + 1) * SK + r] = kv.y;
      kcT[(d + 2) * SK + r] = kv.z; kcT[(d + 3) * SK + r] = kv.w;
      qcT[(d + 0) * SK + r] = qv.x; qcT[(d + 1) * SK + r] = qv.y;
      qcT[(d + 2) * SK + r] = qv.z; qcT[(d + 3) * SK + r] = qv.w;
    }
  }
  __syncthreads();
  if (tid == 0) {
    float a = 0.f;
    for (int i = 0; i < 64; ++i) { a += cs[i]; cs[i] = a; }
  }
  __syncthreads();
  if (tid < 64) {
    float gv_ = __expf(cs[tid]);
    wk[tid]  = bet[tid] * gv_;
  }
  for (int e = tid; e < 4096; e += 256) {
    int i = e >> 6, s = e & 63;
    float av = 0.f;
    if (s < i) {
      float acc = 0.f;
      for (int d = 0; d < 128; ++d) acc += kcT[d * SK + i] * kcT[d * SK + s];
      av = bet[i] * __expf(cs[i] - cs[s]) * acc;
    }
    Amat[i * 65 + s] = av;
  }
  for (int e = tid; e < 4096; e += 256) {
    int s = e >> 6, i = e & 63;
    float outv = 0.f;
    if (s <= i) {
      float acc = 0.f;
      for (int d = 0; d < 128; ++d) acc += qcT[d * SK + i] * kcT[d * SK + s];
      outv = __expf(cs[i] - cs[s]) * acc;
    }
    BTm[cb * 4096 + (size_t)s * 64 + i] = outv;
  }
  __syncthreads();
  if (tid < 64) {
    int j = tid;
    for (int i = 0; i < 64; ++i) {
      float m = (i == j) ? 1.f : 0.f;
      for (int s = 0; s < i; ++s) m -= Amat[i * 65 + s] * Mmat[s * 65 + j];
      Mmat[i * 65 + j] = m;
    }
  }
  __syncthreads();
  for (int e = tid; e < 2048; e += 256) {
    int i = e & 63, d0 = ((e >> 6) & 31) * 4;
    float a0 = 0, a1 = 0, a2 = 0, a3 = 0;
#pragma unroll 4
    for (int s = 0; s < 64; ++s) {
      float m_ = Mmat[i * 65 + s] * wk[s];
      a0 = fmaf(m_, kcT[(d0 + 0) * SK + s], a0);
      a1 = fmaf(m_, kcT[(d0 + 1) * SK + s], a1);
      a2 = fmaf(m_, kcT[(d0 + 2) * SK + s], a2);
      a3 = fmaf(m_, kcT[(d0 + 3) * SK + s], a3);
    }
    float4 w4 = {a0, a1, a2, a3};
    *(float4*)&Kbar[cb * 8192 + (size_t)i * 128 + d0] = w4;
  }
  __syncthreads();
  {
    int r = tid >> 2, j0 = (tid & 3) * 64;
    const float4* vg = (const float4*)&V[((size_t)(b * Tc + t0 + r)) * 2048 + h * 256 + j0];
#pragma unroll
    for (int m = 0; m < 16; ++m) *(float4*)&vld[r * 256 + j0 + m * 4] = vg[m];
  }
  __syncthreads();
  for (int e = tid; e < 4096; e += 256) {
    int i = e >> 6, j0 = (e & 63) * 4;
    float a0 = 0, a1 = 0, a2 = 0, a3 = 0;
    for (int s = 0; s < 64; ++s) {
      float m_ = Mmat[i * 65 + s] * bet[s];
      float4 vv = *(const float4*)&vld[s * 256 + j0];
      a0 = fmaf(m_, vv.x, a0); a1 = fmaf(m_, vv.y, a1);
      a2 = fmaf(m_, vv.z, a2); a3 = fmaf(m_, vv.w, a3);
    }
    float4 o4 = {a0, a1, a2, a3};
    *(float4*)&V[((size_t)(b * Tc + t0 + i)) * 2048 + h * 256 + j0] = o4;
  }
}

// ---------------- Phase 2: serial-over-chunks, column-parallel ----------------
// XCD co-location (this round's change): grid is (bh, jb) so linear block id
// = bh + jb*16 -> id%8 = bh%8 -> all 16 jb-siblings of a bh land on ONE XCD,
// sharing its L2 for the 16x-reread Kbar/BTm/q/k staging (was 131MB HBM fetch).
__global__ __launch_bounds__(256) void phase2(const float* __restrict__ KbarG,
                                              const float* __restrict__ BTmG,
                                              const float* __restrict__ GL,
                                              const float* __restrict__ Qp,
                                              const float* __restrict__ Kp,
                                              const float* __restrict__ VBAR,
                                              float* __restrict__ O) {
  __shared__ float S[16 * 132];
  __shared__ float KbL[64 * 128];
  __shared__ float qcL[64 * 128];
  __shared__ float K2L[64 * 128];
  __shared__ float BcL[64 * 64];
  __shared__ float uL[64 * 20];
  __shared__ float csL[64], rsL[64], gamL[64];
  const int tid = threadIdx.x;
  const int l = tid & 63, w = tid >> 6;
  const int jb = blockIdx.y, bh = blockIdx.x;   // SWAPPED: bh fast-varying
  const int b = bh >> 3, h = bh & 7;
  const int i = l;
  const int j0 = w * 4;
  const int swzi = (i & 7) << 2;
  const int d0u = (tid & 31) * 4;
  const int jq = tid >> 5;
  const size_t colbase = (size_t)h * 256 + jb * 16;

  for (int e = tid; e < 16 * 132; e += 256) S[e] = 0.f;

  for (int c = 0; c < NCHUNK; ++c) {
    const size_t cb = (size_t)bh * NCHUNK + c;
    const int bT0 = b * Tc + c * CHUNK;
    __syncthreads();
    if (tid < 64) {
      float gi = GL[((size_t)(bT0 + tid)) * 8 + h];
#pragma unroll
      for (int off = 1; off < 64; off <<= 1) {
        float p = __shfl_up(gi, off);
        if (tid >= off) gi += p;
      }
      csL[tid] = gi;
    }
    {
      const char* kbg = (const char*)(KbarG + cb * 8192);
#pragma unroll
      for (int ic = 0; ic < 8; ++ic) {
        int ch = ic * 4 + w;
        int row = 2 * ch + (l >> 5);
        int inrow = (l & 31) * 16;
        int swz = inrow ^ ((row & 7) << 4);
        gload16(kbg + row * 512 + swz, (char*)KbL + ch * 1024);
        gload16((const char*)(Qp + ((size_t)(bT0 + row)) * 1024 + h * 128) + swz,
                (char*)qcL + ch * 1024);
        gload16((const char*)(Kp + ((size_t)(bT0 + row)) * 1024 + h * 128) + inrow,
                (char*)K2L + ch * 1024);
      }
      const char* btg = (const char*)(BTmG + cb * 4096);
#pragma unroll
      for (int ic = 0; ic < 4; ++ic) {
        int ch = ic * 4 + w;
        gload16(btg + ch * 1024 + l * 16, (char*)BcL + ch * 1024);
      }
    }
    __syncthreads();
    if (tid < 64) {
      gamL[tid] = __expf(csL[tid]);
      rsL[tid]  = __expf(csL[63] - csL[tid]);
    }
    float ua[4] = {}, ra[4] = {};
#pragma unroll 4
    for (int d = 0; d < 128; d += 4) {
      int ds = d ^ swzi;
      float4 kb = *(const float4*)&KbL[i * 128 + ds];
      float4 qg = *(const float4*)&qcL[i * 128 + ds];
#pragma unroll
      for (int jj = 0; jj < 4; ++jj) {
        float4 s4 = *(const float4*)&S[(j0 + jj) * 132 + d];
        ua[jj] = fmaf(kb.x, s4.x, fmaf(kb.y, s4.y, fmaf(kb.z, s4.z, fmaf(kb.w, s4.w, ua[jj]))));
        ra[jj] = fmaf(qg.x, s4.x, fmaf(qg.y, s4.y, fmaf(qg.z, s4.z, fmaf(qg.w, s4.w, ra[jj]))));
      }
    }
    float4 vb = *(const float4*)&VBAR[((size_t)(bT0 + i)) * 2048 + colbase + j0];
    float4 uf = {vb.x - ua[0], vb.y - ua[1], vb.z - ua[2], vb.w - ua[3]};
    *(float4*)&uL[i * 20 + j0] = uf;
    __syncthreads();
    float ba[4] = {};
#pragma unroll 4
    for (int s = 0; s < 64; ++s) {
      float bv = BcL[s * 64 + i];
      float4 u4 = *(const float4*)&uL[s * 20 + j0];
      ba[0] = fmaf(bv, u4.x, ba[0]); ba[1] = fmaf(bv, u4.y, ba[1]);
      ba[2] = fmaf(bv, u4.z, ba[2]); ba[3] = fmaf(bv, u4.w, ba[3]);
    }
    float gi = gamL[i];
    float4 o4 = {gi * ra[0] + ba[0], gi * ra[1] + ba[1],
                 gi * ra[2] + ba[2], gi * ra[3] + ba[3]};
    *(float4*)&O[((size_t)(bT0 + i)) * 2048 + colbase + j0] = o4;
    float sa[2][4] = {};
#pragma unroll 4
    for (int s = 0; s < 64; ++s) {
      float4 k2 = *(const float4*)&K2L[s * 128 + d0u];
      float rv = rsL[s];
      float u0 = uL[s * 20 + 2 * jq] * rv;
      float u1 = uL[s * 20 + 2 * jq + 1] * rv;
      sa[0][0] = fmaf(k2.x, u0, sa[0][0]); sa[0][1] = fmaf(k2.y, u0, sa[0][1]);
      sa[0][2] = fmaf(k2.z, u0, sa[0][2]); sa[0][3] = fmaf(k2.w, u0, sa[0][3]);
      sa[1][0] = fmaf(k2.x, u1, sa[1][0]); sa[1][1] = fmaf(k2.y, u1, sa[1][1]);
      sa[1][2] = fmaf(k2.z, u1, sa[1][2]); sa[1][3] = fmaf(k2.w, u1, sa[1][3]);
    }
    float gC = gamL[63];
#pragma unroll
    for (int jj = 0; jj < 2; ++jj) {
      float4 sv = *(const float4*)&S[(2 * jq + jj) * 132 + d0u];
      sv.x = fmaf(gC, sv.x, sa[jj][0]); sv.y = fmaf(gC, sv.y, sa[jj][1]);
      sv.z = fmaf(gC, sv.z, sa[jj][2]); sv.w = fmaf(gC, sv.w, sa[jj][3]);
      *(float4*)&S[(2 * jq + jj) * 132 + d0u] = sv;
    }
  }
}

// ---------------- fused gated RMSNorm -> bf16 output ----------------
__global__ __launch_bounds__(256) void gated_rmsnorm(const float* __restrict__ O,
                                                     const float* __restrict__ GV,
                                                     const float* __restrict__ NW,
                                                     unsigned short* __restrict__ OO) {
  int w    = blockIdx.x * 4 + (threadIdx.x >> 6);
  int lane = threadIdx.x & 63;
  size_t base = (size_t)w * DVc;
  float4 o4 = *(const float4*)&O[base + lane * 4];
  float ss = o4.x * o4.x + o4.y * o4.y + o4.z * o4.z + o4.w * o4.w;
#pragma unroll
  for (int m = 1; m < 64; m <<= 1) ss += __shfl_xor(ss, m);
  float r = rsqrtf(ss * (1.f / 256.f) + 1e-5f);
  float4 g4 = *(const float4*)&GV[base + lane * 4];
  float4 w4 = *(const float4*)&NW[lane * 4];
  float4 out;
  out.x = o4.x * r * w4.x * (g4.x / (1.f + __expf(-g4.x)));
  out.y = o4.y * r * w4.y * (g4.y / (1.f + __expf(-g4.y)));
  out.z = o4.z * r * w4.z * (g4.z / (1.f + __expf(-g4.z)));
  out.w = o4.w * r * w4.w * (g4.w / (1.f + __expf(-g4.w)));
  short4v ob = {(short)f2bf(out.x), (short)f2bf(out.y), (short)f2bf(out.z), (short)f2bf(out.w)};
  *(short4v*)&OO[base + lane * 4] = ob;
}

// ---------------- launcher ----------------
extern "C" void kernel_launch(void* const* d_in, const int* in_sizes, int n_in,
                              void* d_out, int out_size, void* d_ws, size_t ws_size,
                              hipStream_t stream) {
  const float* x       = (const float*)d_in[0];
  const float* Wq      = (const float*)d_in[1];
  const float* Wk      = (const float*)d_in[2];
  const float* Wv      = (const float*)d_in[3];
  const float* conv_q  = (const float*)d_in[4];
  const float* conv_k  = (const float*)d_in[5];
  const float* conv_v  = (const float*)d_in[6];
  const float* Wb      = (const float*)d_in[7];
  const float* Wa      = (const float*)d_in[8];
  const float* A_log   = (const float*)d_in[9];
  const float* dt_bias = (const float*)d_in[10];
  const float* Wg      = (const float*)d_in[11];
  const float* norm_w  = (const float*)d_in[12];
  const float* Wo      = (const float*)d_in[13];
  float* out = (float*)d_out;
  float* ws  = (float*)d_ws;

  unsigned short* xb  = (unsigned short*)(ws + OF_XB);
  unsigned short* WqT = (unsigned short*)(ws + OF_WQT);
  unsigned short* WkT = (unsigned short*)(ws + OF_WKT);
  unsigned short* WvT = (unsigned short*)(ws + OF_WVT);
  unsigned short* WgT = (unsigned short*)(ws + OF_WGT);
  unsigned short* WoT = (unsigned short*)(ws + OF_WOT);
  unsigned short* oob = (unsigned short*)(ws + OF_OOB);
  float* qpre  = ws + OF_QPRE;
  float* kpre  = ws + OF_KPRE;
  float* vpre  = ws + OF_VPRE;
  float* q     = ws + OF_Q;
  float* k     = ws + OF_K;
  float* v     = ws + OF_V;
  float* glog  = ws + OF_G;
  float* beta  = ws + OF_BETA;
  float* Kbar  = ws + OF_KBAR;
  float* BTm   = ws + OF_BTG;
  float* o     = ws + OF_O;
  float* gv    = ws + OF_GV;

  dim3 blk(256);

  // bf16 conversions (early)
  cvt_bf16<<<dim3(2048), blk, 0, stream>>>(x, xb);
  transposeW<<<dim3(16, 16), blk, 0, stream>>>(Wq, WqT, 1024, 1024);
  transposeW<<<dim3(16, 16), blk, 0, stream>>>(Wk, WkT, 1024, 1024);
  transposeW<<<dim3(32, 16), blk, 0, stream>>>(Wv, WvT, 1024, 2048);

  // projections (MFMA NT)
  gemm_nt<64><<<dim3(16, 16), blk, 0, stream>>>(xb, WqT, qpre, BT_ROWS, 1024, 1024);
  gemm_nt<64><<<dim3(16, 16), blk, 0, stream>>>(xb, WkT, kpre, BT_ROWS, 1024, 1024);
  gemm_nt<128><<<dim3(16, 16), blk, 0, stream>>>(xb, WvT, vpre, BT_ROWS, 2048, 1024);

  // beta + log-decay
  beta_g_kernel<<<dim3(BT_ROWS * Hc / 4), blk, 0, stream>>>(x, Wb, Wa, A_log, dt_bias, beta, glog);

  // causal conv + silu
  conv_silu<<<dim3(1024 / 256, Tc / 32, Bc), blk, 0, stream>>>(qpre, conv_q, q, 1024);
  conv_silu<<<dim3(1024 / 256, Tc / 32, Bc), blk, 0, stream>>>(kpre, conv_k, k, 1024);
  conv_silu<<<dim3(2048 / 256, Tc / 32, Bc), blk, 0, stream>>>(vpre, conv_v, v, 2048);

  // l2norm q (scaled) and k
  l2norm_qk<<<dim3(BT_ROWS * Hc / 4), blk, 0, stream>>>(q, k);

  // chunked delta rule
  phase1<<<dim3(NCHUNK, Bc * Hc), blk, 0, stream>>>(q, k, v, glog, beta, Kbar, BTm);
  phase2<<<dim3(Bc * Hc, 16), blk, 0, stream>>>(Kbar, BTm, glog, q, k, v, o);  // (bh, jb)

  // gv = x @ Wg (late: WgT over dead Kbar region)
  transposeW<<<dim3(32, 16), blk, 0, stream>>>(Wg, WgT, 1024, 2048);
  gemm_nt<128><<<dim3(16, 16), blk, 0, stream>>>(xb, WgT, gv, BT_ROWS, 2048, 1024);

  // gated rmsnorm -> bf16 oob
  transposeW<<<dim3(16, 32), blk, 0, stream>>>(Wo, WoT, 2048, 1024);
  gated_rmsnorm<<<dim3(BT_ROWS * Hc / 4), blk, 0, stream>>>(o, gv, norm_w, oob);

  // out = oob @ WoT
  gemm_nt<64><<<dim3(16, 16), blk, 0, stream>>>(oob, WoT, out, BT_ROWS, 1024, 2048);
}

// Round 9
// 489.078 us; speedup vs baseline: 4.2615x; 1.2222x over previous
//
#include <hip/hip_runtime.h>
#include <hip/hip_bf16.h>
#include <math.h>

// Problem dims (fixed by reference)
constexpr int Bc = 2, Tc = 1024, Dc = 1024, Hc = 8, DKc = 128, DVc = 256;
constexpr int BT_ROWS = Bc * Tc;                // 2048 rows
constexpr float QSCALE = 0.08838834764831845f;  // 128^-0.5
constexpr int NCHUNK = 16, CHUNK = 64;          // T = 16 chunks of 64

// ---------------- workspace layout (float offsets), extent = 16,809,984 f (proven) ----
// 0..1M    xb bf16
// 1..2M    Kb16 bf16 [256cb][64][128]   (phase1->phase2) ; late: WgT over it
// 2..3M    K2T16 bf16 [256cb][128][64]  (phase1->phase2) ; late: WoT over it
// 3..3.5M  BT16 bf16 [256cb][64][64]    (phase1->phase2)
// 4..6M    qpre ; then v=vbar (4..8M) ; late: oob bf16
// 6..8M    kpre
// 8..12M   vpre ; then: o bf16 (8..10M), qg16 bf16 (10..11M), spare 11..12M
// 12..14M  q f32 (dead after phase1) ; early WqT/WkT/WvT ; late gv (12..16M)
// 14..16M  k f32 (dead after phase1)
// 16M..    glog, beta
constexpr size_t OF_XB   = 0;
constexpr size_t OF_KB16 = 1048576;
constexpr size_t OF_K2T  = 2097152;
constexpr size_t OF_BT16 = 3145728;
constexpr size_t OF_QPRE = 4194304;
constexpr size_t OF_KPRE = 6291456;
constexpr size_t OF_VPRE = 8388608;
constexpr size_t OF_Q    = 12582912;
constexpr size_t OF_K    = 14680064;
constexpr size_t OF_V    = 4194304;   // vbar, over qpre+kpre
constexpr size_t OF_G    = 16777216;
constexpr size_t OF_BETA = 16793600;
constexpr size_t OF_OB   = 8388608;   // o bf16 [2048][2048] (2M fl-eq) over vpre
constexpr size_t OF_QG   = 10485760;  // qg16 bf16 [256cb][64][128] (1M fl-eq) over vpre
constexpr size_t OF_GV   = 12582912;  // over q+k (dead after phase1)
constexpr size_t OF_OOB  = 4194304;   // over v (dead after phase2)
constexpr size_t OF_WQT  = 12582912;  // early, die before conv writes q
constexpr size_t OF_WKT  = 13107200;
constexpr size_t OF_WVT  = 13631488;
constexpr size_t OF_WGT  = 1048576;   // late, over Kb16
constexpr size_t OF_WOT  = 2097152;   // late, over K2T16

using short8 = __attribute__((ext_vector_type(8))) short;
using short4v = __attribute__((ext_vector_type(4))) short;
using f32x4  = __attribute__((ext_vector_type(4))) float;

__device__ inline unsigned short f2bf(float f) {  // RNE fp32->bf16
  unsigned int u = __builtin_bit_cast(unsigned int, f);
  u += 0x7FFFu + ((u >> 16) & 1u);
  return (unsigned short)(u >> 16);
}
__device__ inline float bf2f(unsigned short u) {
  unsigned int x = (unsigned int)u << 16;
  return __builtin_bit_cast(float, x);
}

// async global->LDS 16B copy (dest wave-uniform base + lane*16; src per-lane)
__device__ inline void gload16(const void* g, void* l) {
  __builtin_amdgcn_global_load_lds(
      (const __attribute__((address_space(1))) unsigned int*)g,
      (__attribute__((address_space(3))) unsigned int*)l, 16, 0, 0);
}

// ---------------- fp32 -> bf16 elementwise ----------------
__global__ __launch_bounds__(256) void cvt_bf16(const float* __restrict__ X,
                                                unsigned short* __restrict__ Y) {
  int i = (blockIdx.x * 256 + threadIdx.x) * 4;
  float4 f = *(const float4*)&X[i];
  short4v o = {(short)f2bf(f.x), (short)f2bf(f.y), (short)f2bf(f.z), (short)f2bf(f.w)};
  *(short4v*)&Y[i] = o;
}

// ---------------- W[K][N] fp32 -> WT[N][K] bf16 (64x64 tiles) ----------------
__global__ __launch_bounds__(256) void transposeW(const float* __restrict__ W,
                                                  unsigned short* __restrict__ WT,
                                                  int K, int N) {
  __shared__ unsigned short Ls[64 * 66];
  const int n0 = blockIdx.x * 64, k0 = blockIdx.y * 64;
  const int t = threadIdx.x;
  {
    int r = t >> 2, c0 = (t & 3) * 16;
    const float* src = &W[(size_t)(k0 + r) * N + n0 + c0];
#pragma unroll
    for (int m = 0; m < 4; ++m) {
      float4 f = *(const float4*)&src[m * 4];
      unsigned short* p = &Ls[r * 66 + c0 + m * 4];
      p[0] = f2bf(f.x); p[1] = f2bf(f.y); p[2] = f2bf(f.z); p[3] = f2bf(f.w);
    }
  }
  __syncthreads();
  {
    int n = t >> 2, k4 = (t & 3) * 16;
    short8 o0, o1;
#pragma unroll
    for (int j = 0; j < 8; ++j) {
      o0[j] = (short)Ls[(k4 + j) * 66 + n];
      o1[j] = (short)Ls[(k4 + 8 + j) * 66 + n];
    }
    unsigned short* dst = &WT[(size_t)(n0 + n) * K + k0 + k4];
    *(short8*)dst = o0;
    *(short8*)(dst + 8) = o1;
  }
}

// ---------------- NT bf16-MFMA GEMM (proven R7) ----------------
template <int TN>
__global__ __launch_bounds__(256) void gemm_nt(const unsigned short* __restrict__ A,
                                               const unsigned short* __restrict__ BT,
                                               float* __restrict__ C,
                                               int M, int N, int K) {
  constexpr int NF = TN / 32;
  __shared__ unsigned short As[128 * 64];
  __shared__ unsigned short Bs[TN * 64];
  const int tid = threadIdx.x, l = tid & 63, w = tid >> 6;
  const int m0 = blockIdx.y * 128, n0 = blockIdx.x * TN;
  const int wm = (w >> 1) * 64, wn = (w & 1) * (TN / 2);
  const int fr = l & 15, hk = l >> 4;
  const int srow = l >> 3, swin = l & 7;
  f32x4 acc[4][NF] = {};

  for (int k0 = 0; k0 < K; k0 += 64) {
#pragma unroll
    for (int i = 0; i < 4; ++i) {
      int ch = i * 4 + w;
      int row = ch * 8 + srow;
      gload16((const char*)(A + (size_t)(m0 + row) * K + k0) + ((swin ^ (row & 7)) * 16),
              (char*)As + ch * 1024);
    }
#pragma unroll
    for (int i = 0; i < TN / 32; ++i) {
      int ch = i * 4 + w;
      int row = ch * 8 + srow;
      gload16((const char*)(BT + (size_t)(n0 + row) * K + k0) + ((swin ^ (row & 7)) * 16),
              (char*)Bs + ch * 1024);
    }
    __syncthreads();
#pragma unroll
    for (int ks = 0; ks < 2; ++ks) {
      short8 a[4], b[NF];
#pragma unroll
      for (int mf = 0; mf < 4; ++mf) {
        int row = wm + mf * 16 + fr;
        a[mf] = *(const short8*)((const char*)As + row * 128 + (((hk + 4 * ks) ^ (row & 7)) * 16));
      }
#pragma unroll
      for (int nf = 0; nf < NF; ++nf) {
        int row = wn + nf * 16 + fr;
        b[nf] = *(const short8*)((const char*)Bs + row * 128 + (((hk + 4 * ks) ^ (row & 7)) * 16));
      }
#pragma unroll
      for (int mf = 0; mf < 4; ++mf)
#pragma unroll
        for (int nf = 0; nf < NF; ++nf)
          acc[mf][nf] = __builtin_amdgcn_mfma_f32_16x16x32_bf16(a[mf], b[nf], acc[mf][nf], 0, 0, 0);
    }
    __syncthreads();
  }
  const int orow = (l >> 4) * 4;
#pragma unroll
  for (int mf = 0; mf < 4; ++mf)
#pragma unroll
    for (int nf = 0; nf < NF; ++nf)
#pragma unroll
      for (int r = 0; r < 4; ++r)
        C[(size_t)(m0 + wm + mf * 16 + orow + r) * N + n0 + wn + nf * 16 + fr] = acc[mf][nf][r];
}

// ---------------- depthwise causal conv1d (K=4) + silu ----------------
__global__ __launch_bounds__(256) void conv_silu(const float* __restrict__ X,
                                                 const float* __restrict__ W,
                                                 float* __restrict__ Y, int C) {
  int c = blockIdx.x * 256 + threadIdx.x;
  if (c >= C) return;
  int b  = blockIdx.z;
  int t0 = blockIdx.y * 32;
  float4 w = *(const float4*)&W[c * 4];
  const float* xp = X + (size_t)b * Tc * C + c;
  float* yp = Y + (size_t)b * Tc * C + c;
  float x0 = (t0 >= 3) ? xp[(size_t)(t0 - 3) * C] : 0.f;
  float x1 = (t0 >= 2) ? xp[(size_t)(t0 - 2) * C] : 0.f;
  float x2 = (t0 >= 1) ? xp[(size_t)(t0 - 1) * C] : 0.f;
  for (int t = t0; t < t0 + 32; ++t) {
    float x3 = xp[(size_t)t * C];
    float a  = w.x * x0 + w.y * x1 + w.z * x2 + w.w * x3;
    float y  = a / (1.f + __expf(-a));
    yp[(size_t)t * C] = y;
    x0 = x1; x1 = x2; x2 = x3;
  }
}

// ---------------- beta + g_log ----------------
__global__ __launch_bounds__(256) void beta_g_kernel(const float* __restrict__ X,
                                                     const float* __restrict__ Wb,
                                                     const float* __restrict__ Wa,
                                                     const float* __restrict__ A_log,
                                                     const float* __restrict__ dt_bias,
                                                     float* __restrict__ beta,
                                                     float* __restrict__ glog) {
  int w    = blockIdx.x * 4 + (threadIdx.x >> 6);
  int lane = threadIdx.x & 63;
  int h  = w & 7;
  int bt = w >> 3;
  const float* x = X + (size_t)bt * Dc;
  float sb = 0.f, sa = 0.f;
#pragma unroll
  for (int i = 0; i < 16; ++i) {
    int d = lane + 64 * i;
    float xv = x[d];
    sb = fmaf(xv, Wb[d * 8 + h], sb);
    sa = fmaf(xv, Wa[d * 8 + h], sa);
  }
#pragma unroll
  for (int m = 1; m < 64; m <<= 1) {
    sb += __shfl_xor(sb, m);
    sa += __shfl_xor(sa, m);
  }
  if (lane == 0) {
    beta[w] = 1.f / (1.f + expf(-sb));
    float z  = sa + dt_bias[h];
    float sp = (z > 20.f) ? z : log1pf(expf(z));
    glog[w]  = -expf(A_log[h]) * sp;
  }
}

// ---------------- l2norm q (scaled) and k ----------------
__global__ __launch_bounds__(256) void l2norm_qk(float* __restrict__ Q, float* __restrict__ K) {
  int w    = blockIdx.x * 4 + (threadIdx.x >> 6);
  int lane = threadIdx.x & 63;
  int h = w & 7;
  size_t bt = (size_t)(w >> 3);
  float* qp = Q + bt * (Hc * DKc) + h * DKc + lane * 2;
  float* kp = K + bt * (Hc * DKc) + h * DKc + lane * 2;
  float2 q2 = *(float2*)qp;
  float2 k2 = *(float2*)kp;
  float sq = q2.x * q2.x + q2.y * q2.y;
  float sk = k2.x * k2.x + k2.y * k2.y;
#pragma unroll
  for (int m = 1; m < 64; m <<= 1) {
    sq += __shfl_xor(sq, m);
    sk += __shfl_xor(sk, m);
  }
  float rq = rsqrtf(sq + 1e-6f) * QSCALE;
  float rk = rsqrtf(sk + 1e-6f);
  q2.x *= rq; q2.y *= rq;
  k2.x *= rk; k2.y *= rk;
  *(float2*)qp = q2;
  *(float2*)kp = k2;
}

// ---------------- Phase 1: per (bh, chunk) precompute ----------------
// Emits bf16 MFMA operands: Kb16[i][128], BT16[i][s], K2T16[d][s], qg16[i][128];
// vbar f32 in-place over V.
__global__ __launch_bounds__(256) void phase1(const float* __restrict__ Q,
                                              const float* __restrict__ K,
                                              float* __restrict__ V,
                                              const float* __restrict__ G,
                                              const float* __restrict__ BETA,
                                              unsigned short* __restrict__ Kb16,
                                              unsigned short* __restrict__ BT16,
                                              unsigned short* __restrict__ K2T16,
                                              unsigned short* __restrict__ QG16) {
  constexpr int SK = 68;
  __shared__ float sm[25984];
  float* kcT  = sm;            // [128][68]
  float* qcT  = sm + 8704;     // [128][68]
  float* vld  = sm;            // [64][256] (reuse after barrier)
  float* Amat = sm + 17408;    // [64][65]
  float* Mmat = sm + 21568;    // [64][65]
  float* cs   = sm + 25728;
  float* bet  = sm + 25856;
  float* wk   = sm + 25920;
  const int tid = threadIdx.x;
  const int c = blockIdx.x, bh = blockIdx.y;
  const int b = bh >> 3, h = bh & 7;
  const int t0 = c * CHUNK;
  const size_t cb = (size_t)bh * NCHUNK + c;

  if (tid < 64) {
    cs[tid]  = G[((size_t)(b * Tc + t0 + tid)) * 8 + h];
    bet[tid] = BETA[((size_t)(b * Tc + t0 + tid)) * 8 + h];
  }
  {
    int r = tid >> 2, dq = (tid & 3) * 32;
    const float4* kg = (const float4*)&K[((size_t)(b * Tc + t0 + r)) * 1024 + h * 128 + dq];
    const float4* qg = (const float4*)&Q[((size_t)(b * Tc + t0 + r)) * 1024 + h * 128 + dq];
#pragma unroll
    for (int m = 0; m < 8; ++m) {
      float4 kv = kg[m], qv = qg[m];
      int d = dq + m * 4;
      kcT[(d + 0) * SK + r] = kv.x; kcT[(d + 1) * SK + r] = kv.y;
      kcT[(d + 2) * SK + r] = kv.z; kcT[(d + 3) * SK + r] = kv.w;
      qcT[(d + 0) * SK + r] = qv.x; qcT[(d + 1) * SK + r] = qv.y;
      qcT[(d + 2) * SK + r] = qv.z; qcT[(d + 3) * SK + r] = qv.w;
      short4v qb = {(short)f2bf(qv.x), (short)f2bf(qv.y), (short)f2bf(qv.z), (short)f2bf(qv.w)};
      *(short4v*)&QG16[cb * 8192 + (size_t)r * 128 + d] = qb;
    }
  }
  __syncthreads();
  if (tid == 0) {
    float a = 0.f;
    for (int i = 0; i < 64; ++i) { a += cs[i]; cs[i] = a; }
  }
  __syncthreads();
  if (tid < 64) {
    float gv_ = __expf(cs[tid]);
    wk[tid]  = bet[tid] * gv_;
  }
  for (int e = tid; e < 4096; e += 256) {
    int i = e >> 6, s = e & 63;
    float av = 0.f;
    if (s < i) {
      float acc = 0.f;
      for (int d = 0; d < 128; ++d) acc += kcT[d * SK + i] * kcT[d * SK + s];
      av = bet[i] * __expf(cs[i] - cs[s]) * acc;
    }
    Amat[i * 65 + s] = av;
  }
  // BT i-major bf16: BT16[i][s] = (s<=i) ? exp(cs_i-cs_s) * (q_i . k_s) : 0
  for (int e = tid; e < 4096; e += 256) {
    int i = e >> 6, s = e & 63;
    float outv = 0.f;
    if (s <= i) {
      float acc = 0.f;
      for (int d = 0; d < 128; ++d) acc += qcT[d * SK + i] * kcT[d * SK + s];
      outv = __expf(cs[i] - cs[s]) * acc;
    }
    BT16[cb * 4096 + (size_t)i * 64 + s] = f2bf(outv);
  }
  // K2T bf16: K2T16[d][s] = k_s[d]
  for (int e = tid; e < 8192; e += 256) {
    int d = e >> 6, s = e & 63;
    K2T16[cb * 8192 + (size_t)d * 64 + s] = f2bf(kcT[d * SK + s]);
  }
  __syncthreads();
  if (tid < 64) {
    int j = tid;
    for (int i = 0; i < 64; ++i) {
      float m = (i == j) ? 1.f : 0.f;
      for (int s = 0; s < i; ++s) m -= Amat[i * 65 + s] * Mmat[s * 65 + j];
      Mmat[i * 65 + j] = m;
    }
  }
  __syncthreads();
  // Kb16[i][d] = sum_s M[i][s]*beta_s*gamma_s*K[s][d]  (bf16)
  for (int e = tid; e < 2048; e += 256) {
    int i = e & 63, d0 = ((e >> 6) & 31) * 4;
    float a0 = 0, a1 = 0, a2 = 0, a3 = 0;
#pragma unroll 4
    for (int s = 0; s < 64; ++s) {
      float m_ = Mmat[i * 65 + s] * wk[s];
      a0 = fmaf(m_, kcT[(d0 + 0) * SK + s], a0);
      a1 = fmaf(m_, kcT[(d0 + 1) * SK + s], a1);
      a2 = fmaf(m_, kcT[(d0 + 2) * SK + s], a2);
      a3 = fmaf(m_, kcT[(d0 + 3) * SK + s], a3);
    }
    short4v w4 = {(short)f2bf(a0), (short)f2bf(a1), (short)f2bf(a2), (short)f2bf(a3)};
    *(short4v*)&Kb16[cb * 8192 + (size_t)i * 128 + d0] = w4;
  }
  __syncthreads();
  {
    int r = tid >> 2, j0 = (tid & 3) * 64;
    const float4* vg = (const float4*)&V[((size_t)(b * Tc + t0 + r)) * 2048 + h * 256 + j0];
#pragma unroll
    for (int m = 0; m < 16; ++m) *(float4*)&vld[r * 256 + j0 + m * 4] = vg[m];
  }
  __syncthreads();
  for (int e = tid; e < 4096; e += 256) {
    int i = e >> 6, j0 = (e & 63) * 4;
    float a0 = 0, a1 = 0, a2 = 0, a3 = 0;
    for (int s = 0; s < 64; ++s) {
      float m_ = Mmat[i * 65 + s] * bet[s];
      float4 vv = *(const float4*)&vld[s * 256 + j0];
      a0 = fmaf(m_, vv.x, a0); a1 = fmaf(m_, vv.y, a1);
      a2 = fmaf(m_, vv.z, a2); a3 = fmaf(m_, vv.w, a3);
    }
    float4 o4 = {a0, a1, a2, a3};
    *(float4*)&V[((size_t)(b * Tc + t0 + i)) * 2048 + h * 256 + j0] = o4;
  }
}

// ---------------- Phase 2: MFMA chunked recurrence ----------------
// Block (bh=blockIdx.x for XCD co-location, jb): 16 cols; S[16][128] f32 master in
// LDS + bf16 shadow Sb. Per chunk, per wave w (rows i in [16w,16w+16)):
//   u = vbar - Kb@S^T, ra = qg@S^T   (4+4 MFMA)
//   bu = Bc@u (2), dS = ru^T@K2 (4); o = gam*ra + bu; S = gC*S + dS; rebuild Sb.
// All operands bf16, accum f32. Frag convention = gemm_nt (A[row][k], B[col][k],
// byte = ko ^ ((row&7)<<4), source pre-swizzled via gload16).
__global__ __launch_bounds__(256) void phase2(const unsigned short* __restrict__ Kb16,
                                              const unsigned short* __restrict__ BT16,
                                              const unsigned short* __restrict__ K2T16,
                                              const unsigned short* __restrict__ QG16,
                                              const float* __restrict__ GL,
                                              const float* __restrict__ VBAR,
                                              unsigned short* __restrict__ Ob) {
  __shared__ float S[16 * 132];             // master state [j][d]
  __shared__ unsigned short Sb[16 * 128];   // bf16 shadow, swizzled
  __shared__ unsigned short KbL[64 * 128];
  __shared__ unsigned short qgL[64 * 128];
  __shared__ unsigned short K2L[128 * 64];
  __shared__ unsigned short BtL[64 * 64];
  __shared__ unsigned short ubT[16 * 64];   // u^T [j][i], swizzled
  __shared__ unsigned short rubT[16 * 64];  // (rs*u)^T [j][i], swizzled
  __shared__ float rsL[64], gamL[64];
  const int tid = threadIdx.x, l = tid & 63, w = tid >> 6;
  const int bh = blockIdx.x, jb = blockIdx.y;
  const int b = bh >> 3, h = bh & 7;
  const int fr = l & 15, hk = l >> 4;
  const size_t colbase = (size_t)h * 256 + jb * 16;

  for (int e = tid; e < 16 * 132; e += 256) S[e] = 0.f;
  for (int e = tid; e < 2048; e += 256) Sb[e] = 0;
  __syncthreads();

  for (int c = 0; c < NCHUNK; ++c) {
    const size_t cb = (size_t)bh * NCHUNK + c;
    const int bT0 = b * Tc + c * CHUNK;
    // ---- wave0: decay scan -> gam/rs ----
    if (tid < 64) {
      float gi = GL[((size_t)(bT0 + tid)) * 8 + h];
#pragma unroll
      for (int off = 1; off < 64; off <<= 1) {
        float p = __shfl_up(gi, off);
        if (tid >= off) gi += p;
      }
      float c63 = __shfl(gi, 63);
      gamL[tid] = __expf(gi);
      rsL[tid]  = __expf(c63 - gi);
    }
    // ---- stage (bf16, source pre-swizzled) ----
    {
      const char* kb = (const char*)Kb16 + cb * 16384;
      const char* qg = (const char*)QG16 + cb * 16384;
#pragma unroll
      for (int ic = 0; ic < 4; ++ic) {      // 256B rows, 4 rows/KB
        int ch = ic * 4 + w;
        int row = ch * 4 + (l >> 4);
        int sw = ((l & 15) * 16) ^ ((row & 7) << 4);
        gload16(kb + row * 256 + sw, (char*)KbL + ch * 1024);
        gload16(qg + row * 256 + sw, (char*)qgL + ch * 1024);
      }
      const char* kt = (const char*)K2T16 + cb * 16384;
#pragma unroll
      for (int ic = 0; ic < 4; ++ic) {      // 128B rows, 8 rows/KB
        int ch = ic * 4 + w;
        int row = ch * 8 + (l >> 3);
        int sw = ((l & 7) * 16) ^ ((row & 7) << 4);
        gload16(kt + row * 128 + sw, (char*)K2L + ch * 1024);
      }
      const char* bt = (const char*)BT16 + cb * 8192;
#pragma unroll
      for (int ic = 0; ic < 2; ++ic) {
        int ch = ic * 4 + w;
        int row = ch * 8 + (l >> 3);
        int sw = ((l & 7) * 16) ^ ((row & 7) << 4);
        gload16(bt + row * 128 + sw, (char*)BtL + ch * 1024);
      }
    }
    __syncthreads();  // stage + gam/rs ready (drains vmcnt)
    // ---- u/ra MFMA: D(i,j), i-block = wave ----
    f32x4 uac = {0.f, 0.f, 0.f, 0.f}, rac = {0.f, 0.f, 0.f, 0.f};
    {
      int arow = w * 16 + fr;
      const char* kbr = (const char*)KbL + arow * 256;
      const char* qgr = (const char*)qgL + arow * 256;
      const char* sbr = (const char*)Sb + fr * 256;
      int asw = (arow & 7) << 4, bsw = (fr & 7) << 4;
#pragma unroll
      for (int ks = 0; ks < 4; ++ks) {
        int ko = hk * 16 + ks * 64;
        short8 a1 = *(const short8*)(kbr + (ko ^ asw));
        short8 a2 = *(const short8*)(qgr + (ko ^ asw));
        short8 bb = *(const short8*)(sbr + (ko ^ bsw));
        uac = __builtin_amdgcn_mfma_f32_16x16x32_bf16(a1, bb, uac, 0, 0, 0);
        rac = __builtin_amdgcn_mfma_f32_16x16x32_bf16(a2, bb, rac, 0, 0, 0);
      }
    }
    // ---- u = vbar - uac ; write ubT, rubT (bf16, swizzled) ----
    {
      int i0 = w * 16 + hk * 4;
      short4v up, rp;
#pragma unroll
      for (int r = 0; r < 4; ++r) {
        int i = i0 + r;
        float vb = VBAR[((size_t)(bT0 + i)) * 2048 + colbase + fr];
        float uv = vb - uac[r];
        up[r] = (short)f2bf(uv);
        rp[r] = (short)f2bf(uv * rsL[i]);
      }
      int off = fr * 128 + ((i0 * 2) ^ ((fr & 7) << 4));
      *(short4v*)((char*)ubT + off)  = up;
      *(short4v*)((char*)rubT + off) = rp;
    }
    __syncthreads();  // ubT/rubT ready
    // ---- bu = Bc@u (D(i,j)) ----
    f32x4 bac = {0.f, 0.f, 0.f, 0.f};
    {
      int arow = w * 16 + fr;
      const char* btr = (const char*)BtL + arow * 128;
      const char* ubr = (const char*)ubT + fr * 128;
      int asw = (arow & 7) << 4, bsw = (fr & 7) << 4;
#pragma unroll
      for (int ks = 0; ks < 2; ++ks) {
        int ko = hk * 16 + ks * 64;
        short8 a = *(const short8*)(btr + (ko ^ asw));
        short8 bb = *(const short8*)(ubr + (ko ^ bsw));
        bac = __builtin_amdgcn_mfma_f32_16x16x32_bf16(a, bb, bac, 0, 0, 0);
      }
    }
    // ---- o = gam_i*ra + bu -> bf16 global ----
    {
      int i0 = w * 16 + hk * 4;
#pragma unroll
      for (int r = 0; r < 4; ++r) {
        int i = i0 + r;
        float ov = gamL[i] * rac[r] + bac[r];
        Ob[((size_t)(bT0 + i)) * 2048 + colbase + fr] = f2bf(ov);
      }
    }
    // ---- dS = ru^T @ K2 : D(j, d), wave w owns d-blocks 2w, 2w+1 ----
    f32x4 sac0 = {0.f, 0.f, 0.f, 0.f}, sac1 = {0.f, 0.f, 0.f, 0.f};
    {
      const char* rur = (const char*)rubT + fr * 128;
      int asw = (fr & 7) << 4;
      int d0c = (2 * w) * 16 + fr, d1c = (2 * w + 1) * 16 + fr;
      const char* k0r = (const char*)K2L + d0c * 128;
      const char* k1r = (const char*)K2L + d1c * 128;
      int b0sw = (d0c & 7) << 4, b1sw = (d1c & 7) << 4;
#pragma unroll
      for (int ks = 0; ks < 2; ++ks) {
        int ko = hk * 16 + ks * 64;
        short8 a = *(const short8*)(rur + (ko ^ asw));
        short8 b0 = *(const short8*)(k0r + (ko ^ b0sw));
        short8 b1 = *(const short8*)(k1r + (ko ^ b1sw));
        sac0 = __builtin_amdgcn_mfma_f32_16x16x32_bf16(a, b0, sac0, 0, 0, 0);
        sac1 = __builtin_amdgcn_mfma_f32_16x16x32_bf16(a, b1, sac1, 0, 0, 0);
      }
    }
    // ---- S RMW (each element owned by exactly one lane) ----
    {
      float gC = gamL[63];
#pragma unroll
      for (int r = 0; r < 4; ++r) {
        int j = hk * 4 + r;
        int a0 = j * 132 + (2 * w) * 16 + fr;
        int a1 = j * 132 + (2 * w + 1) * 16 + fr;
        S[a0] = fmaf(gC, S[a0], sac0[r]);
        S[a1] = fmaf(gC, S[a1], sac1[r]);
      }
    }
    __syncthreads();  // S updated
    // ---- rebuild Sb (bf16, swizzled) ----
    {
      int j = tid >> 4, d0 = (tid & 15) * 8;
      float4 s0 = *(const float4*)&S[j * 132 + d0];
      float4 s1 = *(const float4*)&S[j * 132 + d0 + 4];
      short8 sb8 = {(short)f2bf(s0.x), (short)f2bf(s0.y), (short)f2bf(s0.z), (short)f2bf(s0.w),
                    (short)f2bf(s1.x), (short)f2bf(s1.y), (short)f2bf(s1.z), (short)f2bf(s1.w)};
      *(short8*)((char*)Sb + j * 256 + ((d0 * 2) ^ ((j & 7) << 4))) = sb8;
    }
    __syncthreads();  // Sb ready; safe to restage
  }
}

// ---------------- fused gated RMSNorm: o bf16 in -> oob bf16 out ----------------
__global__ __launch_bounds__(256) void gated_rmsnorm(const unsigned short* __restrict__ O,
                                                     const float* __restrict__ GV,
                                                     const float* __restrict__ NW,
                                                     unsigned short* __restrict__ OO) {
  int w    = blockIdx.x * 4 + (threadIdx.x >> 6);
  int lane = threadIdx.x & 63;
  size_t base = (size_t)w * DVc;
  short4v o4v = *(const short4v*)&O[base + lane * 4];
  float o0 = bf2f((unsigned short)o4v[0]), o1 = bf2f((unsigned short)o4v[1]);
  float o2 = bf2f((unsigned short)o4v[2]), o3 = bf2f((unsigned short)o4v[3]);
  float ss = o0 * o0 + o1 * o1 + o2 * o2 + o3 * o3;
#pragma unroll
  for (int m = 1; m < 64; m <<= 1) ss += __shfl_xor(ss, m);
  float r = rsqrtf(ss * (1.f / 256.f) + 1e-5f);
  float4 g4 = *(const float4*)&GV[base + lane * 4];
  float4 w4 = *(const float4*)&NW[lane * 4];
  float out0 = o0 * r * w4.x * (g4.x / (1.f + __expf(-g4.x)));
  float out1 = o1 * r * w4.y * (g4.y / (1.f + __expf(-g4.y)));
  float out2 = o2 * r * w4.z * (g4.z / (1.f + __expf(-g4.z)));
  float out3 = o3 * r * w4.w * (g4.w / (1.f + __expf(-g4.w)));
  short4v ob = {(short)f2bf(out0), (short)f2bf(out1), (short)f2bf(out2), (short)f2bf(out3)};
  *(short4v*)&OO[base + lane * 4] = ob;
}

// ---------------- launcher ----------------
extern "C" void kernel_launch(void* const* d_in, const int* in_sizes, int n_in,
                              void* d_out, int out_size, void* d_ws, size_t ws_size,
                              hipStream_t stream) {
  const float* x       = (const float*)d_in[0];
  const float* Wq      = (const float*)d_in[1];
  const float* Wk      = (const float*)d_in[2];
  const float* Wv      = (const float*)d_in[3];
  const float* conv_q  = (const float*)d_in[4];
  const float* conv_k  = (const float*)d_in[5];
  const float* conv_v  = (const float*)d_in[6];
  const float* Wb      = (const float*)d_in[7];
  const float* Wa      = (const float*)d_in[8];
  const float* A_log   = (const float*)d_in[9];
  const float* dt_bias = (const float*)d_in[10];
  const float* Wg      = (const float*)d_in[11];
  const float* norm_w  = (const float*)d_in[12];
  const float* Wo      = (const float*)d_in[13];
  float* out = (float*)d_out;
  float* ws  = (float*)d_ws;

  unsigned short* xb   = (unsigned short*)(ws + OF_XB);
  unsigned short* Kb16 = (unsigned short*)(ws + OF_KB16);
  unsigned short* K2T  = (unsigned short*)(ws + OF_K2T);
  unsigned short* BT16 = (unsigned short*)(ws + OF_BT16);
  unsigned short* QG16 = (unsigned short*)(ws + OF_QG);
  unsigned short* ob   = (unsigned short*)(ws + OF_OB);
  unsigned short* WqT  = (unsigned short*)(ws + OF_WQT);
  unsigned short* WkT  = (unsigned short*)(ws + OF_WKT);
  unsigned short* WvT  = (unsigned short*)(ws + OF_WVT);
  unsigned short* WgT  = (unsigned short*)(ws + OF_WGT);
  unsigned short* WoT  = (unsigned short*)(ws + OF_WOT);
  unsigned short* oob  = (unsigned short*)(ws + OF_OOB);
  float* qpre  = ws + OF_QPRE;
  float* kpre  = ws + OF_KPRE;
  float* vpre  = ws + OF_VPRE;
  float* q     = ws + OF_Q;
  float* k     = ws + OF_K;
  float* v     = ws + OF_V;
  float* glog  = ws + OF_G;
  float* beta  = ws + OF_BETA;
  float* gv    = ws + OF_GV;

  dim3 blk(256);

  // bf16 conversions (early)
  cvt_bf16<<<dim3(2048), blk, 0, stream>>>(x, xb);
  transposeW<<<dim3(16, 16), blk, 0, stream>>>(Wq, WqT, 1024, 1024);
  transposeW<<<dim3(16, 16), blk, 0, stream>>>(Wk, WkT, 1024, 1024);
  transposeW<<<dim3(32, 16), blk, 0, stream>>>(Wv, WvT, 1024, 2048);

  // projections (MFMA NT)
  gemm_nt<64><<<dim3(16, 16), blk, 0, stream>>>(xb, WqT, qpre, BT_ROWS, 1024, 1024);
  gemm_nt<64><<<dim3(16, 16), blk, 0, stream>>>(xb, WkT, kpre, BT_ROWS, 1024, 1024);
  gemm_nt<128><<<dim3(16, 16), blk, 0, stream>>>(xb, WvT, vpre, BT_ROWS, 2048, 1024);

  // beta + log-decay
  beta_g_kernel<<<dim3(BT_ROWS * Hc / 4), blk, 0, stream>>>(x, Wb, Wa, A_log, dt_bias, beta, glog);

  // causal conv + silu
  conv_silu<<<dim3(1024 / 256, Tc / 32, Bc), blk, 0, stream>>>(qpre, conv_q, q, 1024);
  conv_silu<<<dim3(1024 / 256, Tc / 32, Bc), blk, 0, stream>>>(kpre, conv_k, k, 1024);
  conv_silu<<<dim3(2048 / 256, Tc / 32, Bc), blk, 0, stream>>>(vpre, conv_v, v, 2048);

  // l2norm q (scaled) and k
  l2norm_qk<<<dim3(BT_ROWS * Hc / 4), blk, 0, stream>>>(q, k);

  // chunked delta rule
  phase1<<<dim3(NCHUNK, Bc * Hc), blk, 0, stream>>>(q, k, v, glog, beta, Kb16, BT16, K2T, QG16);
  phase2<<<dim3(Bc * Hc, 16), blk, 0, stream>>>(Kb16, BT16, K2T, QG16, glog, v, ob);

  // gv = x @ Wg (late: WgT over dead Kb16)
  transposeW<<<dim3(32, 16), blk, 0, stream>>>(Wg, WgT, 1024, 2048);
  gemm_nt<128><<<dim3(16, 16), blk, 0, stream>>>(xb, WgT, gv, BT_ROWS, 2048, 1024);

  // gated rmsnorm -> bf16 oob
  transposeW<<<dim3(16, 32), blk, 0, stream>>>(Wo, WoT, 2048, 1024);
  gated_rmsnorm<<<dim3(BT_ROWS * Hc / 4), blk, 0, stream>>>(ob, gv, norm_w, oob);

  // out = oob @ WoT
  gemm_nt<64><<<dim3(16, 16), blk, 0, stream>>>(oob, WoT, out, BT_ROWS, 1024, 2048);
}